// Round 1
// baseline (1451.013 us; speedup 1.0000x reference)
//
#include <hip/hip_runtime.h>
#include <math.h>

#define TT   32
#define NN   100000
#define FF   2
#define ROW  64        // TT*FF floats per node row
#define EE   1600000
#define MAXIT 20

__device__ __forceinline__ float sigmoidf_(float x) { return 1.0f / (1.0f + expf(-x)); }

// ---------------------------------------------------------------------------
// Zero the per-iteration "remaining zero nodes" counters (ws is 0xAA-poisoned)
__global__ void k_zero_rem(int* __restrict__ rem) {
    int i = threadIdx.x;
    if (i <= MAXIT) rem[i] = 0;
}

// ---------------------------------------------------------------------------
// masked = where(mask, x, 0), transposed [T,N,F] -> node-major [N][T*F]
__global__ void k_mask_transpose(const float* __restrict__ x,
                                 const int* __restrict__ mask,
                                 float* __restrict__ xx) {
    int j = blockIdx.x * blockDim.x + threadIdx.x;   // t-major flat index
    const int total = TT * NN * FF;
    if (j >= total) return;
    int f = j & 1;
    int n = (j >> 1) % NN;
    int t = j / (NN * FF);
    float v = x[j];
    v = mask[n] ? v : 0.0f;
    xx[(size_t)n * ROW + t * FF + f] = v;
}

// ---------------------------------------------------------------------------
// Initial has_data / has_zero flags + rem[0] (= any(xx==0) for while-cond)
__global__ void k_flags(const float* __restrict__ xx,
                        int* __restrict__ hd, int* __restrict__ hz,
                        int* __restrict__ rem) {
    int gtid = blockIdx.x * blockDim.x + threadIdx.x;
    int wave = gtid >> 6, lane = gtid & 63;
    int nwaves = (gridDim.x * blockDim.x) >> 6;
    for (int n = wave; n < NN; n += nwaves) {
        float v = xx[(size_t)n * ROW + lane];
        unsigned long long nz = __ballot(v != 0.0f);
        if (lane == 0) {
            hd[n] = (nz != 0ull) ? 1 : 0;
            int z = (nz != ~0ull) ? 1 : 0;   // some lane saw a zero
            hz[n] = z;
            if (z) atomicAdd(&rem[0], 1);
        }
    }
}

// ---------------------------------------------------------------------------
// Iteration step A: zero agg row + cnt for nodes that still have zeros
__global__ void k_zero_agg(const int* __restrict__ rem, int k,
                           const int* __restrict__ hz,
                           float* __restrict__ agg, float* __restrict__ cnt) {
    if (rem[k - 1] == 0) return;   // converged: no-op iteration
    int gtid = blockIdx.x * blockDim.x + threadIdx.x;
    int wave = gtid >> 6, lane = gtid & 63;
    int nwaves = (gridDim.x * blockDim.x) >> 6;
    for (int n = wave; n < NN; n += nwaves) {
        if (!hz[n]) continue;
        agg[(size_t)n * ROW + lane] = 0.0f;
        if (lane == 0) cnt[n] = 0.0f;
    }
}

// ---------------------------------------------------------------------------
// Iteration step B: edge scatter. One wave per edge; 64 lanes = 64 row elems.
// Skips are exact: !has_data[src] => valid=0 contributes nothing;
//                  !has_zero[dst] => fill is a no-op for dst.
__global__ void k_scatter(const int* __restrict__ rem, int k,
                          const int* __restrict__ ei,
                          const int* __restrict__ hd, const int* __restrict__ hz,
                          const float* __restrict__ xx,
                          float* __restrict__ agg, float* __restrict__ cnt) {
    if (rem[k - 1] == 0) return;
    int gtid = blockIdx.x * blockDim.x + threadIdx.x;
    int wave = gtid >> 6, lane = gtid & 63;
    int nwaves = (gridDim.x * blockDim.x) >> 6;
    for (int e = wave; e < EE; e += nwaves) {
        int dst = ei[EE + e];
        if (!hz[dst]) continue;
        int src = ei[e];
        if (!hd[src]) continue;
        float v = xx[(size_t)src * ROW + lane];
        atomicAdd(&agg[(size_t)dst * ROW + lane], v);
        if (lane == 0) atomicAdd(&cnt[dst], 1.0f);
    }
}

// ---------------------------------------------------------------------------
// Iteration step C: fill zeros with mean, recompute flags, count remaining
__global__ void k_fill(const int* __restrict__ remprev_unused, int k,
                       int* __restrict__ hd, int* __restrict__ hz,
                       float* __restrict__ xx,
                       const float* __restrict__ agg, const float* __restrict__ cnt,
                       int* __restrict__ rem) {
    if (rem[k - 1] == 0) return;
    int gtid = blockIdx.x * blockDim.x + threadIdx.x;
    int wave = gtid >> 6, lane = gtid & 63;
    int nwaves = (gridDim.x * blockDim.x) >> 6;
    for (int n = wave; n < NN; n += nwaves) {
        if (!hz[n]) continue;
        float c = cnt[n];
        float denom = (c > 0.0f) ? c : 1.0f;
        size_t idx = (size_t)n * ROW + lane;
        float v = xx[idx];
        if (v == 0.0f) v = agg[idx] / denom;
        xx[idx] = v;
        unsigned long long nz = __ballot(v != 0.0f);
        if (lane == 0) {
            hd[n] = (nz != 0ull) ? 1 : 0;
            int z = (nz != ~0ull) ? 1 : 0;
            hz[n] = z;
            if (z) atomicAdd(&rem[k], 1);
        }
    }
}

// ---------------------------------------------------------------------------
// LSTM: one thread per node. hidden=2, gates i,f,g,o (4x2=8), T=32 steps.
__global__ void k_lstm(const float* __restrict__ xx,
                       const float* __restrict__ wih, const float* __restrict__ whh,
                       const float* __restrict__ bih, const float* __restrict__ bhh,
                       float* __restrict__ out) {
    int n = blockIdx.x * blockDim.x + threadIdx.x;
    if (n >= NN) return;
    float Wi[8][2], Wh[8][2], B[8];
#pragma unroll
    for (int kk = 0; kk < 8; kk++) {
        Wi[kk][0] = wih[kk * 2]; Wi[kk][1] = wih[kk * 2 + 1];
        Wh[kk][0] = whh[kk * 2]; Wh[kk][1] = whh[kk * 2 + 1];
        B[kk] = bih[kk] + bhh[kk];
    }
    float h0 = 0.f, h1 = 0.f, c0 = 0.f, c1 = 0.f;
    const float* row = xx + (size_t)n * ROW;
#pragma unroll 4
    for (int t = 0; t < TT; t++) {
        float x0 = row[t * 2], x1 = row[t * 2 + 1];
        float g[8];
#pragma unroll
        for (int kk = 0; kk < 8; kk++)
            g[kk] = B[kk] + Wi[kk][0] * x0 + Wi[kk][1] * x1 + Wh[kk][0] * h0 + Wh[kk][1] * h1;
        float i0 = sigmoidf_(g[0]), i1 = sigmoidf_(g[1]);
        float f0 = sigmoidf_(g[2]), f1 = sigmoidf_(g[3]);
        float g0 = tanhf(g[4]),     g1 = tanhf(g[5]);
        float o0 = sigmoidf_(g[6]), o1 = sigmoidf_(g[7]);
        c0 = f0 * c0 + i0 * g0;
        c1 = f1 * c1 + i1 * g1;
        h0 = o0 * tanhf(c0);
        h1 = o1 * tanhf(c1);
        out[(size_t)t * NN * FF + n * 2 + 0] = h0;
        out[(size_t)t * NN * FF + n * 2 + 1] = h1;
    }
}

// ---------------------------------------------------------------------------
extern "C" void kernel_launch(void* const* d_in, const int* in_sizes, int n_in,
                              void* d_out, int out_size, void* d_ws, size_t ws_size,
                              hipStream_t stream) {
    const float* x    = (const float*)d_in[0];   // [T,N,F]
    const int*   ei   = (const int*)d_in[1];     // [2,E]
    const int*   mask = (const int*)d_in[2];     // [N] (bool -> int)
    // d_in[3] labels, d_in[4] edge_weight, d_in[5] data: unused by reference
    const float* wih  = (const float*)d_in[6];   // [8,2]
    const float* whh  = (const float*)d_in[7];   // [8,2]
    const float* bih  = (const float*)d_in[8];   // [8]
    const float* bhh  = (const float*)d_in[9];   // [8]
    float* out = (float*)d_out;                  // [T,N,F] fp32

    char* ws = (char*)d_ws;
    float* xx  = (float*)ws;                                   // N*64 f32 = 25.6 MB
    float* cnt = (float*)(ws + (size_t)NN * ROW * 4);          // N f32
    int*   hd  = (int*)(ws + (size_t)NN * ROW * 4 + (size_t)NN * 4);
    int*   hz  = (int*)(ws + (size_t)NN * ROW * 4 + (size_t)NN * 8);
    int*   rem = (int*)(ws + (size_t)NN * ROW * 4 + (size_t)NN * 12);
    float* agg = out;  // reuse d_out (exactly N*64 f32) as agg scratch; LSTM overwrites it last

    k_zero_rem<<<1, 32, 0, stream>>>(rem);
    k_mask_transpose<<<(TT * NN * FF + 255) / 256, 256, 0, stream>>>(x, mask, xx);
    k_flags<<<512, 256, 0, stream>>>(xx, hd, hz, rem);
    for (int k = 1; k <= MAXIT; k++) {
        k_zero_agg<<<512, 256, 0, stream>>>(rem, k, hz, agg, cnt);
        k_scatter<<<1024, 256, 0, stream>>>(rem, k, ei, hd, hz, xx, agg, cnt);
        k_fill<<<512, 256, 0, stream>>>(rem, k, hd, hz, xx, agg, cnt, rem);
    }
    k_lstm<<<(NN + 255) / 256, 256, 0, stream>>>(xx, wih, whh, bih, bhh, out);
}

// Round 2
// 709.984 us; speedup vs baseline: 2.0437x; 2.0437x over previous
//
#include <hip/hip_runtime.h>
#include <math.h>

#define TT    32
#define NN    100000
#define FF    2
#define ROW   64        // TT*FF floats per node row
#define EE    1600000
#define MAXIT 20
#define LDSROW 66       // 64 + 2 pad: (66k+lane)%32 spreads banks, <=2-way = free

__device__ __forceinline__ float fsig(float x) { return 1.0f / (1.0f + __expf(-x)); }
__device__ __forceinline__ float ftanh(float x) { return 2.0f / (1.0f + __expf(-2.0f * x)) - 1.0f; }

// ---------------------------------------------------------------------------
__global__ void k_zero_rem(int* __restrict__ rem) {
    int i = threadIdx.x;
    if (i <= MAXIT) rem[i] = 0;
}

// ---------------------------------------------------------------------------
// Fused: mask + transpose [T,N,F]->[N][64] + per-node flags + agg/cnt zero-init.
// Block = 256 threads, 64 nodes. Both global sides coalesced via LDS tile.
__global__ void k_mt_flags(const float* __restrict__ x, const int* __restrict__ mask,
                           float* __restrict__ xx, float* __restrict__ agg,
                           float* __restrict__ cnt, int* __restrict__ hd,
                           int* __restrict__ hz, int* __restrict__ rem) {
    __shared__ float tile[64 * LDSROW];
    const int n0 = blockIdx.x * 64;
    const int tid = threadIdx.x;

    // Phase 1: coalesced read of 32 t-rows x 128 cols, mask, store to LDS
#pragma unroll
    for (int r = 0; r < 16; r++) {
        int flat = r * 256 + tid;          // 0..4095
        int t = flat >> 7;                 // /128
        int col = flat & 127;              // local (n,f) flat
        int gcol = n0 * 2 + col;
        if (gcol < NN * FF) {
            int n = n0 + (col >> 1);
            float v = x[(size_t)t * (NN * FF) + gcol];
            v = mask[n] ? v : 0.0f;
            tile[(col >> 1) * LDSROW + t * 2 + (col & 1)] = v;
        }
    }
    __syncthreads();

    const int lane = tid & 63, w = tid >> 6;

    // Phase 2: flags, one wave per node (16 nodes/wave), ballot across 64 elems
    int anyz = 0;
    for (int i = 0; i < 16; i++) {
        int ln = w * 16 + i;
        int n = n0 + ln;
        if (n >= NN) break;                        // wave-uniform
        float v = tile[ln * LDSROW + lane];
        unsigned long long nzm = __ballot(v != 0.0f);
        int z = (nzm != ~0ull) ? 1 : 0;
        if (z) agg[(size_t)n * ROW + lane] = 0.0f; // init accumulator for iter 1
        if (lane == 0) {
            hd[n] = (nzm != 0ull) ? 1 : 0;
            hz[n] = z;
            if (z) { cnt[n] = 0.0f; anyz = 1; }
        }
    }
    if (lane == 0 && anyz) rem[0] = 1;             // flag store, no RMW

    // Phase 3: coalesced float4 write of node-major rows
#pragma unroll
    for (int j = 0; j < 4; j++) {
        int flat4 = j * 256 + tid;                 // float4 idx 0..1023
        int ln = flat4 >> 4;
        int n = n0 + ln;
        if (n >= NN) continue;
        int off = (flat4 & 15) * 4;
        float4 v;
        v.x = tile[ln * LDSROW + off + 0];
        v.y = tile[ln * LDSROW + off + 1];
        v.z = tile[ln * LDSROW + off + 2];
        v.w = tile[ln * LDSROW + off + 3];
        *(float4*)(xx + (size_t)n * ROW + off) = v;
    }
}

// ---------------------------------------------------------------------------
// Edge scatter: one wave per contiguous edge chunk (sequential ei reads).
// Skips are exact: !hd[src] => valid=0; !hz[dst] => fill is a no-op for dst.
__global__ void k_scatter(const int* __restrict__ rem, int k,
                          const int* __restrict__ ei,
                          const int* __restrict__ hd, const int* __restrict__ hz,
                          const float* __restrict__ xx,
                          float* __restrict__ agg, float* __restrict__ cnt) {
    if (rem[k - 1] == 0) return;
    const int lane = threadIdx.x & 63;
    const int wave = (blockIdx.x * blockDim.x + threadIdx.x) >> 6;
    const int nw = (gridDim.x * blockDim.x) >> 6;
    const int per = (EE + nw - 1) / nw;
    const int e0 = wave * per;
    const int e1 = (e0 + per < EE) ? e0 + per : EE;
    for (int e = e0; e < e1; e++) {
        int dst = ei[EE + e];                      // broadcast load
        if (!hz[dst]) continue;
        int src = ei[e];
        if (!hd[src]) continue;
        float v = xx[(size_t)src * ROW + lane];
        atomicAdd(&agg[(size_t)dst * ROW + lane], v);
        if (lane == 0) atomicAdd(&cnt[dst], 1.0f);
    }
}

// ---------------------------------------------------------------------------
// Fill zeros with mean, recompute flags, re-zero agg/cnt for next iteration.
__global__ void k_fill(int k, int* __restrict__ hd, int* __restrict__ hz,
                       float* __restrict__ xx, float* __restrict__ agg,
                       float* __restrict__ cnt, int* __restrict__ rem) {
    if (rem[k - 1] == 0) return;
    const int lane = threadIdx.x & 63;
    const int wave = (blockIdx.x * blockDim.x + threadIdx.x) >> 6;
    const int nw = (gridDim.x * blockDim.x) >> 6;
    const int per = (NN + nw - 1) / nw;
    const int n0 = wave * per;
    const int n1 = (n0 + per < NN) ? n0 + per : NN;
    int anyz = 0;
    for (int n = n0; n < n1; n++) {
        if (!hz[n]) continue;                      // wave-uniform
        float c = cnt[n];
        float denom = (c > 0.0f) ? c : 1.0f;
        size_t idx = (size_t)n * ROW + lane;
        float v = xx[idx];
        if (v == 0.0f) v = agg[idx] / denom;
        xx[idx] = v;
        unsigned long long nzm = __ballot(v != 0.0f);
        int z = (nzm != ~0ull) ? 1 : 0;
        if (z) { agg[idx] = 0.0f; anyz = 1; }      // re-init for next iteration
        if (lane == 0) {
            hd[n] = (nzm != 0ull) ? 1 : 0;
            hz[n] = z;
            if (z) cnt[n] = 0.0f;
        }
    }
    if (lane == 0 && anyz) rem[k] = 1;             // flag store, no RMW
}

// ---------------------------------------------------------------------------
// LSTM: one thread per node, hidden=2, gates i,f,g,o. Row prefetched as float4.
__global__ void k_lstm(const float* __restrict__ xx,
                       const float* __restrict__ wih, const float* __restrict__ whh,
                       const float* __restrict__ bih, const float* __restrict__ bhh,
                       float* __restrict__ out) {
    int n = blockIdx.x * blockDim.x + threadIdx.x;
    if (n >= NN) return;
    float Wi[8][2], Wh[8][2], B[8];
#pragma unroll
    for (int kk = 0; kk < 8; kk++) {
        Wi[kk][0] = wih[kk * 2]; Wi[kk][1] = wih[kk * 2 + 1];
        Wh[kk][0] = whh[kk * 2]; Wh[kk][1] = whh[kk * 2 + 1];
        B[kk] = bih[kk] + bhh[kk];
    }
    float4 r4[16];
    const float4* row4 = (const float4*)(xx + (size_t)n * ROW);
#pragma unroll
    for (int i = 0; i < 16; i++) r4[i] = row4[i];
    const float* row = (const float*)r4;

    float h0 = 0.f, h1 = 0.f, c0 = 0.f, c1 = 0.f;
#pragma unroll 4
    for (int t = 0; t < TT; t++) {
        float x0 = row[t * 2], x1 = row[t * 2 + 1];
        float g[8];
#pragma unroll
        for (int kk = 0; kk < 8; kk++)
            g[kk] = B[kk] + Wi[kk][0] * x0 + Wi[kk][1] * x1 + Wh[kk][0] * h0 + Wh[kk][1] * h1;
        float i0 = fsig(g[0]), i1 = fsig(g[1]);
        float f0 = fsig(g[2]), f1 = fsig(g[3]);
        float gg0 = ftanh(g[4]), gg1 = ftanh(g[5]);
        float o0 = fsig(g[6]), o1 = fsig(g[7]);
        c0 = f0 * c0 + i0 * gg0;
        c1 = f1 * c1 + i1 * gg1;
        h0 = o0 * ftanh(c0);
        h1 = o1 * ftanh(c1);
        float2 hv = make_float2(h0, h1);
        *(float2*)(out + (size_t)t * (NN * FF) + n * 2) = hv;
    }
}

// ---------------------------------------------------------------------------
extern "C" void kernel_launch(void* const* d_in, const int* in_sizes, int n_in,
                              void* d_out, int out_size, void* d_ws, size_t ws_size,
                              hipStream_t stream) {
    const float* x    = (const float*)d_in[0];   // [T,N,F]
    const int*   ei   = (const int*)d_in[1];     // [2,E]
    const int*   mask = (const int*)d_in[2];     // [N]
    const float* wih  = (const float*)d_in[6];   // [8,2]
    const float* whh  = (const float*)d_in[7];   // [8,2]
    const float* bih  = (const float*)d_in[8];   // [8]
    const float* bhh  = (const float*)d_in[9];   // [8]
    float* out = (float*)d_out;                  // [T,N,F] fp32

    char* ws = (char*)d_ws;
    float* xx  = (float*)ws;                                       // N*64 f32
    float* cnt = (float*)(ws + (size_t)NN * ROW * 4);              // N f32
    int*   hd  = (int*)  (ws + (size_t)NN * ROW * 4 + (size_t)NN * 4);
    int*   hz  = (int*)  (ws + (size_t)NN * ROW * 4 + (size_t)NN * 8);
    int*   rem = (int*)  (ws + (size_t)NN * ROW * 4 + (size_t)NN * 12);
    float* agg = out;  // d_out (N*64 f32) doubles as agg scratch; LSTM overwrites last

    k_zero_rem<<<1, 32, 0, stream>>>(rem);
    k_mt_flags<<<(NN + 63) / 64, 256, 0, stream>>>(x, mask, xx, agg, cnt, hd, hz, rem);
    for (int k = 1; k <= MAXIT; k++) {
        k_scatter<<<1024, 256, 0, stream>>>(rem, k, ei, hd, hz, xx, agg, cnt);
        k_fill<<<512, 256, 0, stream>>>(k, hd, hz, xx, agg, cnt, rem);
    }
    k_lstm<<<(NN + 255) / 256, 256, 0, stream>>>(xx, wih, whh, bih, bhh, out);
}

// Round 3
// 676.708 us; speedup vs baseline: 2.1442x; 1.0492x over previous
//
#include <hip/hip_runtime.h>
#include <math.h>

#define TT    32
#define NN    100000
#define FF    2
#define ROW   64        // TT*FF floats per node row
#define EE    1600000
#define MAXIT 20
#define LDSROW 66       // 64 + 2 pad for transpose tile
#define BIGIT (1 << 29) // fill_iter value for "no data yet"

__device__ __forceinline__ float fsig(float x) { return 1.0f / (1.0f + __expf(-x)); }
__device__ __forceinline__ float ftanh(float x) { return 2.0f / (1.0f + __expf(-2.0f * x)) - 1.0f; }

// ---------------------------------------------------------------------------
// Zero wl_count[0..31] and wp[0..N) (histogram counters). ws/out are poisoned.
__global__ void k_init(int* __restrict__ wp, int* __restrict__ wl_count) {
    int i = blockIdx.x * blockDim.x + threadIdx.x;
    if (i < 32) wl_count[i] = 0;
    for (int j = i; j < NN; j += gridDim.x * blockDim.x) wp[j] = 0;
}

// ---------------------------------------------------------------------------
// Fused: mask + transpose [T,N,F]->[N][64] + fill_iter init (0 = has data).
__global__ void k_mt_flags(const float* __restrict__ x, const int* __restrict__ mask,
                           float* __restrict__ xx, int* __restrict__ fill_iter) {
    __shared__ float tile[64 * LDSROW];
    const int n0 = blockIdx.x * 64;
    const int tid = threadIdx.x;

#pragma unroll
    for (int r = 0; r < 16; r++) {
        int flat = r * 256 + tid;          // 0..4095
        int t = flat >> 7;
        int col = flat & 127;
        int gcol = n0 * 2 + col;
        if (gcol < NN * FF) {
            int n = n0 + (col >> 1);
            float v = x[(size_t)t * (NN * FF) + gcol];
            v = mask[n] ? v : 0.0f;
            tile[(col >> 1) * LDSROW + t * 2 + (col & 1)] = v;
        }
    }
    __syncthreads();

    const int lane = tid & 63, w = tid >> 6;
    for (int i = 0; i < 16; i++) {
        int ln = w * 16 + i;
        int n = n0 + ln;
        if (n >= NN) break;                          // wave-uniform
        float v = tile[ln * LDSROW + lane];
        unsigned long long nzm = __ballot(v != 0.0f);
        if (lane == 0) fill_iter[n] = (nzm != 0ull) ? 0 : BIGIT;
    }

#pragma unroll
    for (int j = 0; j < 4; j++) {
        int flat4 = j * 256 + tid;
        int ln = flat4 >> 4;
        int n = n0 + ln;
        if (n >= NN) continue;
        int off = (flat4 & 15) * 4;
        float4 v;
        v.x = tile[ln * LDSROW + off + 0];
        v.y = tile[ln * LDSROW + off + 1];
        v.z = tile[ln * LDSROW + off + 2];
        v.w = tile[ln * LDSROW + off + 3];
        *(float4*)(xx + (size_t)n * ROW + off) = v;
    }
}

// ---------------------------------------------------------------------------
// In-degree histogram over dst (into wp).
__global__ void k_hist(const int* __restrict__ ei, int* __restrict__ wp) {
    for (int e = blockIdx.x * blockDim.x + threadIdx.x; e < EE;
         e += gridDim.x * blockDim.x)
        atomicAdd(&wp[ei[EE + e]], 1);
}

// ---------------------------------------------------------------------------
// Single-block exclusive scan of wp[0..N) -> rowptr[0..N]; wp reset to rowptr.
__global__ void k_scan(int* __restrict__ wp, int* __restrict__ rowptr) {
    const int C = 128;                       // 1024*128 >= NN
    __shared__ int sh[1024];
    int t = threadIdx.x;
    int base = t * C;
    int s = 0;
    for (int i = 0; i < C; i++) {
        int idx = base + i;
        if (idx < NN) s += wp[idx];
    }
    sh[t] = s;
    __syncthreads();
    for (int d = 1; d < 1024; d <<= 1) {
        int v = (t >= d) ? sh[t - d] : 0;
        __syncthreads();
        sh[t] += v;
        __syncthreads();
    }
    int excl = (t == 0) ? 0 : sh[t - 1];
    if (t == 0) rowptr[NN] = sh[1023];
    int off = excl;
    for (int i = 0; i < C; i++) {
        int idx = base + i;
        if (idx < NN) {
            int d = wp[idx];
            rowptr[idx] = off;
            wp[idx] = off;                   // becomes the write pointer
            off += d;
        }
    }
}

// ---------------------------------------------------------------------------
// Bucket edges by dst: csr_src[rowptr[dst]..] = src list.
__global__ void k_csr_fill(const int* __restrict__ ei, int* __restrict__ wp,
                           int* __restrict__ csr) {
    for (int e = blockIdx.x * blockDim.x + threadIdx.x; e < EE;
         e += gridDim.x * blockDim.x) {
        int dst = ei[EE + e];
        int src = ei[e];
        int pos = atomicAdd(&wp[dst], 1);
        csr[pos] = src;
    }
}

// ---------------------------------------------------------------------------
// Shared gather body: node n at iteration k. Wave-uniform n.
__device__ __forceinline__ void gather_node(int n, int k, int lane,
                                            const int* __restrict__ rowptr,
                                            const int* __restrict__ csr,
                                            int* __restrict__ fill_iter,
                                            float* __restrict__ xx,
                                            int* __restrict__ wl_next,
                                            int* __restrict__ wl_count) {
    int beg = rowptr[n], end = rowptr[n + 1];
    float acc = 0.0f, cntv = 0.0f;
    int e = beg;
    for (; e + 1 < end; e += 2) {            // unroll 2 for load ILP
        int s0 = csr[e], s1 = csr[e + 1];
        int f0 = fill_iter[s0], f1 = fill_iter[s1];
        if (f0 < k) { acc += xx[(size_t)s0 * ROW + lane]; cntv += 1.0f; }
        if (f1 < k) { acc += xx[(size_t)s1 * ROW + lane]; cntv += 1.0f; }
    }
    if (e < end) {
        int s0 = csr[e];
        if (fill_iter[s0] < k) { acc += xx[(size_t)s0 * ROW + lane]; cntv += 1.0f; }
    }
    size_t idx = (size_t)n * ROW + lane;
    float v = xx[idx];
    if (v == 0.0f && cntv > 0.0f) {
        v = acc / cntv;                      // ref: agg / max(cnt,1); cnt==0 -> stays 0
        xx[idx] = v;
    }
    unsigned long long nzm = __ballot(v != 0.0f);
    if (lane == 0) {
        if (nzm != 0ull && fill_iter[n] > k) fill_iter[n] = k;  // node now has data
        if (nzm != ~0ull) {                  // still has zeros -> next worklist
            int pos = atomicAdd(&wl_count[k], 1);
            wl_next[pos] = n;
        }
    }
}

// ---------------------------------------------------------------------------
// Iteration 1: all nodes, self-detect zeros (no worklist build needed).
__global__ void k_gather_first(const int* __restrict__ rowptr, const int* __restrict__ csr,
                               int* __restrict__ fill_iter, float* __restrict__ xx,
                               int* __restrict__ wl_next, int* __restrict__ wl_count) {
    const int lane = threadIdx.x & 63;
    int wave = (blockIdx.x * blockDim.x + threadIdx.x) >> 6;
    const int nwaves = (gridDim.x * blockDim.x) >> 6;
    for (int n = wave; n < NN; n += nwaves) {
        float v = xx[(size_t)n * ROW + lane];
        unsigned long long zm = __ballot(v == 0.0f);
        if (zm == 0ull) continue;            // wave-uniform: no zeros in row
        gather_node(__builtin_amdgcn_readfirstlane(n), 1, lane,
                    rowptr, csr, fill_iter, xx, wl_next, wl_count);
    }
}

// ---------------------------------------------------------------------------
// Iterations k>=2: worklist-driven.
__global__ void k_gather(int k, const int* __restrict__ wl_prev,
                         int* __restrict__ wl_next, int* __restrict__ wl_count,
                         const int* __restrict__ rowptr, const int* __restrict__ csr,
                         int* __restrict__ fill_iter, float* __restrict__ xx) {
    int cnt = wl_count[k - 1];
    if (cnt == 0) return;
    const int lane = threadIdx.x & 63;
    int wave = (blockIdx.x * blockDim.x + threadIdx.x) >> 6;
    const int nwaves = (gridDim.x * blockDim.x) >> 6;
    for (int w = wave; w < cnt; w += nwaves) {
        int n = __builtin_amdgcn_readfirstlane(wl_prev[w]);
        gather_node(n, k, lane, rowptr, csr, fill_iter, xx, wl_next, wl_count);
    }
}

// ---------------------------------------------------------------------------
// LSTM: one thread per node, hidden=2, gates i,f,g,o.
__global__ void k_lstm(const float* __restrict__ xx,
                       const float* __restrict__ wih, const float* __restrict__ whh,
                       const float* __restrict__ bih, const float* __restrict__ bhh,
                       float* __restrict__ out) {
    int n = blockIdx.x * blockDim.x + threadIdx.x;
    if (n >= NN) return;
    float Wi[8][2], Wh[8][2], B[8];
#pragma unroll
    for (int kk = 0; kk < 8; kk++) {
        Wi[kk][0] = wih[kk * 2]; Wi[kk][1] = wih[kk * 2 + 1];
        Wh[kk][0] = whh[kk * 2]; Wh[kk][1] = whh[kk * 2 + 1];
        B[kk] = bih[kk] + bhh[kk];
    }
    float4 r4[16];
    const float4* row4 = (const float4*)(xx + (size_t)n * ROW);
#pragma unroll
    for (int i = 0; i < 16; i++) r4[i] = row4[i];
    const float* row = (const float*)r4;

    float h0 = 0.f, h1 = 0.f, c0 = 0.f, c1 = 0.f;
#pragma unroll 4
    for (int t = 0; t < TT; t++) {
        float x0 = row[t * 2], x1 = row[t * 2 + 1];
        float g[8];
#pragma unroll
        for (int kk = 0; kk < 8; kk++)
            g[kk] = B[kk] + Wi[kk][0] * x0 + Wi[kk][1] * x1 + Wh[kk][0] * h0 + Wh[kk][1] * h1;
        float i0 = fsig(g[0]), i1 = fsig(g[1]);
        float f0 = fsig(g[2]), f1 = fsig(g[3]);
        float gg0 = ftanh(g[4]), gg1 = ftanh(g[5]);
        float o0 = fsig(g[6]), o1 = fsig(g[7]);
        c0 = f0 * c0 + i0 * gg0;
        c1 = f1 * c1 + i1 * gg1;
        h0 = o0 * ftanh(c0);
        h1 = o1 * ftanh(c1);
        *(float2*)(out + (size_t)t * (NN * FF) + n * 2) = make_float2(h0, h1);
    }
}

// ---------------------------------------------------------------------------
extern "C" void kernel_launch(void* const* d_in, const int* in_sizes, int n_in,
                              void* d_out, int out_size, void* d_ws, size_t ws_size,
                              hipStream_t stream) {
    const float* x    = (const float*)d_in[0];   // [T,N,F]
    const int*   ei   = (const int*)d_in[1];     // [2,E]
    const int*   mask = (const int*)d_in[2];     // [N]
    const float* wih  = (const float*)d_in[6];
    const float* whh  = (const float*)d_in[7];
    const float* bih  = (const float*)d_in[8];
    const float* bhh  = (const float*)d_in[9];
    float* out = (float*)d_out;                  // [T,N,F] fp32

    // ws: xx (25.6 MB) + fill_iter + wl_count
    char* ws = (char*)d_ws;
    float* xx        = (float*)ws;
    int*   fill_iter = (int*)(ws + (size_t)NN * ROW * 4);
    int*   wl_count  = (int*)(ws + (size_t)NN * ROW * 4 + (size_t)NN * 4);

    // d_out doubles as CSR/worklist scratch until k_lstm overwrites it (8 MB < 25.6 MB)
    int* csr    = (int*)d_out;                   // E ints
    int* rowptr = csr + EE;                      // N+1
    int* wp     = rowptr + (NN + 1);             // N
    int* wl_a   = wp + NN;                       // N
    int* wl_b   = wl_a + NN;                     // N

    k_init<<<256, 256, 0, stream>>>(wp, wl_count);
    k_mt_flags<<<(NN + 63) / 64, 256, 0, stream>>>(x, mask, xx, fill_iter);
    k_hist<<<1024, 256, 0, stream>>>(ei, wp);
    k_scan<<<1, 1024, 0, stream>>>(wp, rowptr);
    k_csr_fill<<<1024, 256, 0, stream>>>(ei, wp, csr);
    k_gather_first<<<6250, 256, 0, stream>>>(rowptr, csr, fill_iter, xx, wl_a, wl_count);
    for (int k = 2; k <= MAXIT; k++) {
        int* prev = (k & 1) ? wl_b : wl_a;       // k=2 reads wl_a
        int* next = (k & 1) ? wl_a : wl_b;
        k_gather<<<1024, 256, 0, stream>>>(k, prev, next, wl_count,
                                           rowptr, csr, fill_iter, xx);
    }
    k_lstm<<<(NN + 255) / 256, 256, 0, stream>>>(xx, wih, whh, bih, bhh, out);
}

// Round 4
// 444.653 us; speedup vs baseline: 3.2632x; 1.5219x over previous
//
#include <hip/hip_runtime.h>
#include <math.h>

#define TT    32
#define NN    100000
#define FF    2
#define ROW   64        // TT*FF floats per node row
#define EE    1600000
#define MAXIT 20
#define LDSROW 66       // 64 + 2 pad for transpose tile
#define BIGIT (1 << 29) // fill_iter value for "no data yet"
#define NBLK  ((NN + 1023) / 1024)   // 98 scan blocks

__device__ __forceinline__ float fsig(float x) { return 1.0f / (1.0f + __expf(-x)); }
__device__ __forceinline__ float ftanh(float x) { return 2.0f / (1.0f + __expf(-2.0f * x)) - 1.0f; }

// ---------------------------------------------------------------------------
// Zero wl_count[0..31] and wp[0..N) (histogram counters). ws/out are poisoned.
__global__ void k_init(int* __restrict__ wp, int* __restrict__ wl_count) {
    int i = blockIdx.x * blockDim.x + threadIdx.x;
    if (i < 32) wl_count[i] = 0;
    for (int j = i; j < NN; j += gridDim.x * blockDim.x) wp[j] = 0;
}

// ---------------------------------------------------------------------------
// Fused: mask + transpose [T,N,F]->[N][64] + fill_iter init (0 = has data).
__global__ void k_mt_flags(const float* __restrict__ x, const int* __restrict__ mask,
                           float* __restrict__ xx, int* __restrict__ fill_iter) {
    __shared__ float tile[64 * LDSROW];
    const int n0 = blockIdx.x * 64;
    const int tid = threadIdx.x;

#pragma unroll
    for (int r = 0; r < 16; r++) {
        int flat = r * 256 + tid;          // 0..4095
        int t = flat >> 7;
        int col = flat & 127;
        int gcol = n0 * 2 + col;
        if (gcol < NN * FF) {
            int n = n0 + (col >> 1);
            float v = x[(size_t)t * (NN * FF) + gcol];
            v = mask[n] ? v : 0.0f;
            tile[(col >> 1) * LDSROW + t * 2 + (col & 1)] = v;
        }
    }
    __syncthreads();

    const int lane = tid & 63, w = tid >> 6;
    for (int i = 0; i < 16; i++) {
        int ln = w * 16 + i;
        int n = n0 + ln;
        if (n >= NN) break;                          // wave-uniform
        float v = tile[ln * LDSROW + lane];
        unsigned long long nzm = __ballot(v != 0.0f);
        if (lane == 0) fill_iter[n] = (nzm != 0ull) ? 0 : BIGIT;
    }

#pragma unroll
    for (int j = 0; j < 4; j++) {
        int flat4 = j * 256 + tid;
        int ln = flat4 >> 4;
        int n = n0 + ln;
        if (n >= NN) continue;
        int off = (flat4 & 15) * 4;
        float4 v;
        v.x = tile[ln * LDSROW + off + 0];
        v.y = tile[ln * LDSROW + off + 1];
        v.z = tile[ln * LDSROW + off + 2];
        v.w = tile[ln * LDSROW + off + 3];
        *(float4*)(xx + (size_t)n * ROW + off) = v;
    }
}

// ---------------------------------------------------------------------------
// In-degree histogram over dst (into wp).
__global__ void k_hist(const int* __restrict__ ei, int* __restrict__ wp) {
    for (int e = blockIdx.x * blockDim.x + threadIdx.x; e < EE;
         e += gridDim.x * blockDim.x)
        atomicAdd(&wp[ei[EE + e]], 1);
}

// ---------------------------------------------------------------------------
// Two-level scan, stage 1: per-block sums (98 blocks x 256 thr, int4 loads).
__global__ void k_scan1(const int* __restrict__ wp, int* __restrict__ bsum) {
    __shared__ int wsum[4];
    int b = blockIdx.x, t = threadIdx.x;
    int idx = b * 1024 + t * 4;
    int s = 0;
    if (idx + 3 < NN) {
        int4 v = *(const int4*)(wp + idx);
        s = v.x + v.y + v.z + v.w;
    } else {
        for (int i = 0; i < 4; i++) if (idx + i < NN) s += wp[idx + i];
    }
#pragma unroll
    for (int d = 32; d > 0; d >>= 1) s += __shfl_down(s, d, 64);
    int lane = t & 63, w = t >> 6;
    if (lane == 0) wsum[w] = s;
    __syncthreads();
    if (t == 0) bsum[b] = wsum[0] + wsum[1] + wsum[2] + wsum[3];
}

// ---------------------------------------------------------------------------
// Stage 2: exclusive scan of the 98 block sums (tiny).
__global__ void k_scan2(const int* __restrict__ bsum, int* __restrict__ boff) {
    __shared__ int sh[NBLK];
    int t = threadIdx.x;
    if (t < NBLK) sh[t] = bsum[t];
    __syncthreads();
    if (t == 0) {
        int acc = 0;
        for (int i = 0; i < NBLK; i++) { int v = sh[i]; sh[i] = acc; acc += v; }
    }
    __syncthreads();
    if (t < NBLK) boff[t] = sh[t];
}

// ---------------------------------------------------------------------------
// Stage 3: block-local exclusive scan + block offset -> rowptr, wp(=write ptr).
__global__ void k_scan3(const int* __restrict__ boff,
                        int* __restrict__ rowptr, int* __restrict__ wp) {
    __shared__ int wsum[4];
    int b = blockIdx.x, t = threadIdx.x;
    int lane = t & 63, w = t >> 6;
    int idx = b * 1024 + t * 4;
    int v0 = 0, v1 = 0, v2 = 0, v3 = 0;
    if (idx + 3 < NN) {
        int4 v = *(const int4*)(wp + idx);
        v0 = v.x; v1 = v.y; v2 = v.z; v3 = v.w;
    } else {
        if (idx + 0 < NN) v0 = wp[idx + 0];
        if (idx + 1 < NN) v1 = wp[idx + 1];
        if (idx + 2 < NN) v2 = wp[idx + 2];
        if (idx + 3 < NN) v3 = wp[idx + 3];
    }
    int tsum = v0 + v1 + v2 + v3;
    int incl = tsum;
#pragma unroll
    for (int d = 1; d < 64; d <<= 1) {
        int up = __shfl_up(incl, d, 64);
        if (lane >= d) incl += up;
    }
    if (lane == 63) wsum[w] = incl;
    __syncthreads();
    int woff = 0;
    for (int i = 0; i < w; i++) woff += wsum[i];
    int base = boff[b] + woff + incl - tsum;     // exclusive prefix for v0
    if (idx + 0 < NN) { rowptr[idx + 0] = base;                wp[idx + 0] = base; }
    if (idx + 1 < NN) { rowptr[idx + 1] = base + v0;           wp[idx + 1] = base + v0; }
    if (idx + 2 < NN) { rowptr[idx + 2] = base + v0 + v1;      wp[idx + 2] = base + v0 + v1; }
    if (idx + 3 < NN) { rowptr[idx + 3] = base + v0 + v1 + v2; wp[idx + 3] = base + v0 + v1 + v2; }
    if (b == 0 && t == 0) rowptr[NN] = EE;       // total in-degree == E
}

// ---------------------------------------------------------------------------
// Bucket edges by dst: csr_src[rowptr[dst]..] = src list.
__global__ void k_csr_fill(const int* __restrict__ ei, int* __restrict__ wp,
                           int* __restrict__ csr) {
    for (int e = blockIdx.x * blockDim.x + threadIdx.x; e < EE;
         e += gridDim.x * blockDim.x) {
        int dst = ei[EE + e];
        int src = ei[e];
        int pos = atomicAdd(&wp[dst], 1);
        csr[pos] = src;
    }
}

// ---------------------------------------------------------------------------
// Shared gather body: node n at iteration k. Wave-uniform n.
__device__ __forceinline__ void gather_node(int n, int k, int lane,
                                            const int* __restrict__ rowptr,
                                            const int* __restrict__ csr,
                                            int* __restrict__ fill_iter,
                                            float* __restrict__ xx,
                                            int* __restrict__ wl_next,
                                            int* __restrict__ wl_count) {
    int beg = rowptr[n], end = rowptr[n + 1];
    float acc = 0.0f, cntv = 0.0f;
    int e = beg;
    for (; e + 1 < end; e += 2) {            // unroll 2 for load ILP
        int s0 = csr[e], s1 = csr[e + 1];
        int f0 = fill_iter[s0], f1 = fill_iter[s1];
        if (f0 < k) { acc += xx[(size_t)s0 * ROW + lane]; cntv += 1.0f; }
        if (f1 < k) { acc += xx[(size_t)s1 * ROW + lane]; cntv += 1.0f; }
    }
    if (e < end) {
        int s0 = csr[e];
        if (fill_iter[s0] < k) { acc += xx[(size_t)s0 * ROW + lane]; cntv += 1.0f; }
    }
    size_t idx = (size_t)n * ROW + lane;
    float v = xx[idx];
    if (v == 0.0f && cntv > 0.0f) {
        v = acc / cntv;                      // ref: agg / max(cnt,1); cnt==0 -> stays 0
        xx[idx] = v;
    }
    unsigned long long nzm = __ballot(v != 0.0f);
    if (lane == 0) {
        if (nzm != 0ull && fill_iter[n] > k) fill_iter[n] = k;  // node now has data
        if (nzm != ~0ull) {                  // still has zeros -> next worklist
            int pos = atomicAdd(&wl_count[k], 1);
            wl_next[pos] = n;
        }
    }
}

// ---------------------------------------------------------------------------
// Iteration 1: all nodes, self-detect zeros (no worklist build needed).
__global__ void k_gather_first(const int* __restrict__ rowptr, const int* __restrict__ csr,
                               int* __restrict__ fill_iter, float* __restrict__ xx,
                               int* __restrict__ wl_next, int* __restrict__ wl_count) {
    const int lane = threadIdx.x & 63;
    int wave = (blockIdx.x * blockDim.x + threadIdx.x) >> 6;
    const int nwaves = (gridDim.x * blockDim.x) >> 6;
    for (int n = wave; n < NN; n += nwaves) {
        float v = xx[(size_t)n * ROW + lane];
        unsigned long long zm = __ballot(v == 0.0f);
        if (zm == 0ull) continue;            // wave-uniform: no zeros in row
        gather_node(__builtin_amdgcn_readfirstlane(n), 1, lane,
                    rowptr, csr, fill_iter, xx, wl_next, wl_count);
    }
}

// ---------------------------------------------------------------------------
// Iterations k>=2: worklist-driven.
__global__ void k_gather(int k, const int* __restrict__ wl_prev,
                         int* __restrict__ wl_next, int* __restrict__ wl_count,
                         const int* __restrict__ rowptr, const int* __restrict__ csr,
                         int* __restrict__ fill_iter, float* __restrict__ xx) {
    int cnt = wl_count[k - 1];
    if (cnt == 0) return;
    const int lane = threadIdx.x & 63;
    int wave = (blockIdx.x * blockDim.x + threadIdx.x) >> 6;
    const int nwaves = (gridDim.x * blockDim.x) >> 6;
    for (int w = wave; w < cnt; w += nwaves) {
        int n = __builtin_amdgcn_readfirstlane(wl_prev[w]);
        gather_node(n, k, lane, rowptr, csr, fill_iter, xx, wl_next, wl_count);
    }
}

// ---------------------------------------------------------------------------
// LSTM: one thread per node, hidden=2, gates i,f,g,o.
__global__ void k_lstm(const float* __restrict__ xx,
                       const float* __restrict__ wih, const float* __restrict__ whh,
                       const float* __restrict__ bih, const float* __restrict__ bhh,
                       float* __restrict__ out) {
    int n = blockIdx.x * blockDim.x + threadIdx.x;
    if (n >= NN) return;
    float Wi[8][2], Wh[8][2], B[8];
#pragma unroll
    for (int kk = 0; kk < 8; kk++) {
        Wi[kk][0] = wih[kk * 2]; Wi[kk][1] = wih[kk * 2 + 1];
        Wh[kk][0] = whh[kk * 2]; Wh[kk][1] = whh[kk * 2 + 1];
        B[kk] = bih[kk] + bhh[kk];
    }
    float4 r4[16];
    const float4* row4 = (const float4*)(xx + (size_t)n * ROW);
#pragma unroll
    for (int i = 0; i < 16; i++) r4[i] = row4[i];
    const float* row = (const float*)r4;

    float h0 = 0.f, h1 = 0.f, c0 = 0.f, c1 = 0.f;
#pragma unroll 4
    for (int t = 0; t < TT; t++) {
        float x0 = row[t * 2], x1 = row[t * 2 + 1];
        float g[8];
#pragma unroll
        for (int kk = 0; kk < 8; kk++)
            g[kk] = B[kk] + Wi[kk][0] * x0 + Wi[kk][1] * x1 + Wh[kk][0] * h0 + Wh[kk][1] * h1;
        float i0 = fsig(g[0]), i1 = fsig(g[1]);
        float f0 = fsig(g[2]), f1 = fsig(g[3]);
        float gg0 = ftanh(g[4]), gg1 = ftanh(g[5]);
        float o0 = fsig(g[6]), o1 = fsig(g[7]);
        c0 = f0 * c0 + i0 * gg0;
        c1 = f1 * c1 + i1 * gg1;
        h0 = o0 * ftanh(c0);
        h1 = o1 * ftanh(c1);
        *(float2*)(out + (size_t)t * (NN * FF) + n * 2) = make_float2(h0, h1);
    }
}

// ---------------------------------------------------------------------------
extern "C" void kernel_launch(void* const* d_in, const int* in_sizes, int n_in,
                              void* d_out, int out_size, void* d_ws, size_t ws_size,
                              hipStream_t stream) {
    const float* x    = (const float*)d_in[0];   // [T,N,F]
    const int*   ei   = (const int*)d_in[1];     // [2,E]
    const int*   mask = (const int*)d_in[2];     // [N]
    const float* wih  = (const float*)d_in[6];
    const float* whh  = (const float*)d_in[7];
    const float* bih  = (const float*)d_in[8];
    const float* bhh  = (const float*)d_in[9];
    float* out = (float*)d_out;                  // [T,N,F] fp32

    // ws: xx (25.6 MB) + fill_iter + wl_count + bsum/boff
    char* ws = (char*)d_ws;
    float* xx        = (float*)ws;
    int*   fill_iter = (int*)(ws + (size_t)NN * ROW * 4);
    int*   wl_count  = fill_iter + NN;
    int*   bsum      = wl_count + 32;
    int*   boff      = bsum + 128;

    // d_out doubles as CSR/worklist scratch until k_lstm overwrites it (8 MB < 25.6 MB)
    int* csr    = (int*)d_out;                   // E ints (16B-aligned)
    int* wp     = csr + EE;                      // N     (16B-aligned: EE*4 % 16 == 0)
    int* rowptr = wp + NN;                       // N+1   (16B-aligned: NN*4 % 16 == 0)
    int* wl_a   = rowptr + NN + 4;               // N
    int* wl_b   = wl_a + NN;                     // N

    k_init<<<256, 256, 0, stream>>>(wp, wl_count);
    k_mt_flags<<<(NN + 63) / 64, 256, 0, stream>>>(x, mask, xx, fill_iter);
    k_hist<<<1024, 256, 0, stream>>>(ei, wp);
    k_scan1<<<NBLK, 256, 0, stream>>>(wp, bsum);
    k_scan2<<<1, 128, 0, stream>>>(bsum, boff);
    k_scan3<<<NBLK, 256, 0, stream>>>(boff, rowptr, wp);
    k_csr_fill<<<1024, 256, 0, stream>>>(ei, wp, csr);
    k_gather_first<<<6250, 256, 0, stream>>>(rowptr, csr, fill_iter, xx, wl_a, wl_count);
    for (int k = 2; k <= MAXIT; k++) {
        int* prev = (k & 1) ? wl_b : wl_a;       // k=2 reads wl_a
        int* next = (k & 1) ? wl_a : wl_b;
        int blocks = (k == 2) ? 512 : 128;       // k>=3 is launch-overhead-bound
        k_gather<<<blocks, 256, 0, stream>>>(k, prev, next, wl_count,
                                             rowptr, csr, fill_iter, xx);
    }
    k_lstm<<<(NN + 255) / 256, 256, 0, stream>>>(xx, wih, whh, bih, bhh, out);
}

// Round 5
// 322.759 us; speedup vs baseline: 4.4957x; 1.3777x over previous
//
#include <hip/hip_runtime.h>
#include <math.h>

#define TT    32
#define NN    100000
#define FF    2
#define ROW   64        // TT*FF floats per node row
#define EE    1600000
#define MAXIT 20
#define LDSROW 66       // 64 + 2 pad for transpose tile
#define BIGIT (1 << 29) // fill_iter value for "no data yet"
#define NBLK  ((NN + 1023) / 1024)   // 98 scan blocks

__device__ __forceinline__ float fsig(float x) { return 1.0f / (1.0f + __expf(-x)); }
__device__ __forceinline__ float ftanh(float x) { return 2.0f / (1.0f + __expf(-2.0f * x)) - 1.0f; }

// ---------------------------------------------------------------------------
// Zero wl_count[0..31] and wp[0..N) (histogram counters). ws/out are poisoned.
__global__ void k_init(int* __restrict__ wp, int* __restrict__ wl_count) {
    int i = blockIdx.x * blockDim.x + threadIdx.x;
    if (i < 32) wl_count[i] = 0;
    for (int j = i; j < NN; j += gridDim.x * blockDim.x) wp[j] = 0;
}

// ---------------------------------------------------------------------------
// Fused: mask + transpose [T,N,F]->[N][64] + fill_iter + hz (has-zero) flags.
__global__ void k_mt_flags(const float* __restrict__ x, const int* __restrict__ mask,
                           float* __restrict__ xx, int* __restrict__ fill_iter,
                           unsigned char* __restrict__ hz) {
    __shared__ float tile[64 * LDSROW];
    const int n0 = blockIdx.x * 64;
    const int tid = threadIdx.x;

#pragma unroll
    for (int r = 0; r < 16; r++) {
        int flat = r * 256 + tid;          // 0..4095
        int t = flat >> 7;
        int col = flat & 127;
        int gcol = n0 * 2 + col;
        if (gcol < NN * FF) {
            int n = n0 + (col >> 1);
            float v = x[(size_t)t * (NN * FF) + gcol];
            v = mask[n] ? v : 0.0f;
            tile[(col >> 1) * LDSROW + t * 2 + (col & 1)] = v;
        }
    }
    __syncthreads();

    const int lane = tid & 63, w = tid >> 6;
    for (int i = 0; i < 16; i++) {
        int ln = w * 16 + i;
        int n = n0 + ln;
        if (n >= NN) break;                          // wave-uniform
        float v = tile[ln * LDSROW + lane];
        unsigned long long nzm = __ballot(v != 0.0f);
        if (lane == 0) {
            fill_iter[n] = (nzm != 0ull) ? 0 : BIGIT;
            hz[n] = (nzm != ~0ull) ? 1 : 0;          // row has at least one zero
        }
    }

#pragma unroll
    for (int j = 0; j < 4; j++) {
        int flat4 = j * 256 + tid;
        int ln = flat4 >> 4;
        int n = n0 + ln;
        if (n >= NN) continue;
        int off = (flat4 & 15) * 4;
        float4 v;
        v.x = tile[ln * LDSROW + off + 0];
        v.y = tile[ln * LDSROW + off + 1];
        v.z = tile[ln * LDSROW + off + 2];
        v.w = tile[ln * LDSROW + off + 3];
        *(float4*)(xx + (size_t)n * ROW + off) = v;
    }
}

// ---------------------------------------------------------------------------
// In-degree histogram over dst, ONLY for zero-having dst (others never fill).
__global__ void k_hist(const int* __restrict__ ei, const unsigned char* __restrict__ hz,
                       int* __restrict__ wp) {
    for (int e = blockIdx.x * blockDim.x + threadIdx.x; e < EE;
         e += gridDim.x * blockDim.x) {
        int dst = ei[EE + e];
        if (hz[dst]) atomicAdd(&wp[dst], 1);
    }
}

// ---------------------------------------------------------------------------
// Two-level scan, stage 1: per-block sums (98 blocks x 256 thr, int4 loads).
__global__ void k_scan1(const int* __restrict__ wp, int* __restrict__ bsum) {
    __shared__ int wsum[4];
    int b = blockIdx.x, t = threadIdx.x;
    int idx = b * 1024 + t * 4;
    int s = 0;
    if (idx + 3 < NN) {
        int4 v = *(const int4*)(wp + idx);
        s = v.x + v.y + v.z + v.w;
    } else {
        for (int i = 0; i < 4; i++) if (idx + i < NN) s += wp[idx + i];
    }
#pragma unroll
    for (int d = 32; d > 0; d >>= 1) s += __shfl_down(s, d, 64);
    int lane = t & 63, w = t >> 6;
    if (lane == 0) wsum[w] = s;
    __syncthreads();
    if (t == 0) bsum[b] = wsum[0] + wsum[1] + wsum[2] + wsum[3];
}

// ---------------------------------------------------------------------------
// Stage 2 (fused): block offset from bsum tree-reduce + block-local exclusive
// scan + write rowptr and wp(=write cursor).
__global__ void k_scan3(const int* __restrict__ bsum,
                        int* __restrict__ rowptr, int* __restrict__ wp) {
    __shared__ int sh[128];
    __shared__ int wsum[4];
    int b = blockIdx.x, t = threadIdx.x;
    if (t < 128) sh[t] = (t < b) ? bsum[t] : 0;   // b < NBLK <= 128
    __syncthreads();
#pragma unroll
    for (int d = 64; d > 0; d >>= 1) {
        if (t < d) sh[t] += sh[t + d];
        __syncthreads();
    }
    int blockoff = sh[0];

    int lane = t & 63, w = t >> 6;
    int idx = b * 1024 + t * 4;
    int v0 = 0, v1 = 0, v2 = 0, v3 = 0;
    if (idx + 3 < NN) {
        int4 v = *(const int4*)(wp + idx);
        v0 = v.x; v1 = v.y; v2 = v.z; v3 = v.w;
    } else {
        if (idx + 0 < NN) v0 = wp[idx + 0];
        if (idx + 1 < NN) v1 = wp[idx + 1];
        if (idx + 2 < NN) v2 = wp[idx + 2];
        if (idx + 3 < NN) v3 = wp[idx + 3];
    }
    int tsum = v0 + v1 + v2 + v3;
    int incl = tsum;
#pragma unroll
    for (int d = 1; d < 64; d <<= 1) {
        int up = __shfl_up(incl, d, 64);
        if (lane >= d) incl += up;
    }
    if (lane == 63) wsum[w] = incl;
    __syncthreads();
    int woff = 0;
    for (int i = 0; i < w; i++) woff += wsum[i];
    int base = blockoff + woff + incl - tsum;     // exclusive prefix for v0
    if (idx + 0 < NN) { rowptr[idx + 0] = base;                wp[idx + 0] = base; }
    if (idx + 1 < NN) { rowptr[idx + 1] = base + v0;           wp[idx + 1] = base + v0; }
    if (idx + 2 < NN) { rowptr[idx + 2] = base + v0 + v1;      wp[idx + 2] = base + v0 + v1; }
    if (idx + 3 < NN) { rowptr[idx + 3] = base + v0 + v1 + v2; wp[idx + 3] = base + v0 + v1 + v2; }
    if (b == 0 && t == 0) rowptr[NN] = 0x7fffffff; // sentinel; real end via next hz node is fine
    // NOTE: rowptr[NN] never used for hz nodes' extents because rowptr is a
    // full exclusive scan: hz node n's extent is [rowptr[n], rowptr[n+1]).
    // Set the true total for safety:
    if (b == NBLK - 1 && t == 0) { /* overwritten below by true total */ }
}

// Tiny fixup: rowptr[NN] = total filtered edges (sum of all bsum).
__global__ void k_total(const int* __restrict__ bsum, int* __restrict__ rowptr) {
    __shared__ int sh[128];
    int t = threadIdx.x;
    if (t < 128) sh[t] = (t < NBLK) ? bsum[t] : 0;
    __syncthreads();
#pragma unroll
    for (int d = 64; d > 0; d >>= 1) {
        if (t < d) sh[t] += sh[t + d];
        __syncthreads();
    }
    if (t == 0) rowptr[NN] = sh[0];
}

// ---------------------------------------------------------------------------
// Bucket edges by dst (zero-having dst only): csr[rowptr[dst]..] = src list.
__global__ void k_csr_fill(const int* __restrict__ ei, const unsigned char* __restrict__ hz,
                           int* __restrict__ wp, int* __restrict__ csr) {
    for (int e = blockIdx.x * blockDim.x + threadIdx.x; e < EE;
         e += gridDim.x * blockDim.x) {
        int dst = ei[EE + e];
        if (!hz[dst]) continue;
        int src = ei[e];
        int pos = atomicAdd(&wp[dst], 1);
        csr[pos] = src;
    }
}

// ---------------------------------------------------------------------------
// Shared gather body: node n at iteration k. Wave-uniform n.
__device__ __forceinline__ void gather_node(int n, int k, int lane,
                                            const int* __restrict__ rowptr,
                                            const int* __restrict__ csr,
                                            int* __restrict__ fill_iter,
                                            float* __restrict__ xx,
                                            int* __restrict__ wl_next,
                                            int* __restrict__ wl_count) {
    int beg = rowptr[n], end = rowptr[n + 1];
    float acc = 0.0f, cntv = 0.0f;
    int e = beg;
    for (; e + 1 < end; e += 2) {            // unroll 2 for load ILP
        int s0 = csr[e], s1 = csr[e + 1];
        int f0 = fill_iter[s0], f1 = fill_iter[s1];
        if (f0 < k) { acc += xx[(size_t)s0 * ROW + lane]; cntv += 1.0f; }
        if (f1 < k) { acc += xx[(size_t)s1 * ROW + lane]; cntv += 1.0f; }
    }
    if (e < end) {
        int s0 = csr[e];
        if (fill_iter[s0] < k) { acc += xx[(size_t)s0 * ROW + lane]; cntv += 1.0f; }
    }
    size_t idx = (size_t)n * ROW + lane;
    float v = xx[idx];
    if (v == 0.0f && cntv > 0.0f) {
        v = acc / cntv;                      // ref: agg / max(cnt,1); cnt==0 -> stays 0
        xx[idx] = v;
    }
    unsigned long long nzm = __ballot(v != 0.0f);
    if (lane == 0) {
        if (nzm != 0ull && fill_iter[n] > k) fill_iter[n] = k;  // node now has data
        if (nzm != ~0ull) {                  // still has zeros -> next worklist
            int pos = atomicAdd(&wl_count[k], 1);
            wl_next[pos] = n;
        }
    }
}

// ---------------------------------------------------------------------------
// Iteration 1: all nodes, self-detect zeros (no worklist build needed).
__global__ void k_gather_first(const int* __restrict__ rowptr, const int* __restrict__ csr,
                               int* __restrict__ fill_iter, float* __restrict__ xx,
                               int* __restrict__ wl_next, int* __restrict__ wl_count) {
    const int lane = threadIdx.x & 63;
    int wave = (blockIdx.x * blockDim.x + threadIdx.x) >> 6;
    const int nwaves = (gridDim.x * blockDim.x) >> 6;
    for (int n = wave; n < NN; n += nwaves) {
        float v = xx[(size_t)n * ROW + lane];
        unsigned long long zm = __ballot(v == 0.0f);
        if (zm == 0ull) continue;            // wave-uniform: no zeros in row
        gather_node(__builtin_amdgcn_readfirstlane(n), 1, lane,
                    rowptr, csr, fill_iter, xx, wl_next, wl_count);
    }
}

// ---------------------------------------------------------------------------
// Iterations 2..MAXIT in ONE persistent single-block kernel (worklist is tiny
// after iter 1: only nodes with zero valid neighbors remain).
__global__ __launch_bounds__(1024)
void k_gather_rest(int* __restrict__ wl_a, int* __restrict__ wl_b,
                   int* __restrict__ wl_count,
                   const int* __restrict__ rowptr, const int* __restrict__ csr,
                   int* __restrict__ fill_iter, float* __restrict__ xx) {
    const int lane = threadIdx.x & 63;
    const int wave = threadIdx.x >> 6;       // 0..15
    for (int k = 2; k <= MAXIT; k++) {
        int cnt = atomicAdd(&wl_count[k - 1], 0);   // L2 read, never stale-L1
        if (cnt == 0) break;                        // uniform across block
        int* prev = (k & 1) ? wl_b : wl_a;          // k=2 reads wl_a (gather_first output)
        int* next = (k & 1) ? wl_a : wl_b;
        for (int w = wave; w < cnt; w += 16) {
            int n = __builtin_amdgcn_readfirstlane(prev[w]);
            gather_node(n, k, lane, rowptr, csr, fill_iter, xx, next, wl_count);
        }
        __threadfence();
        __syncthreads();
    }
}

// ---------------------------------------------------------------------------
// LSTM: one thread per node, hidden=2, gates i,f,g,o.
__global__ void k_lstm(const float* __restrict__ xx,
                       const float* __restrict__ wih, const float* __restrict__ whh,
                       const float* __restrict__ bih, const float* __restrict__ bhh,
                       float* __restrict__ out) {
    int n = blockIdx.x * blockDim.x + threadIdx.x;
    if (n >= NN) return;
    float Wi[8][2], Wh[8][2], B[8];
#pragma unroll
    for (int kk = 0; kk < 8; kk++) {
        Wi[kk][0] = wih[kk * 2]; Wi[kk][1] = wih[kk * 2 + 1];
        Wh[kk][0] = whh[kk * 2]; Wh[kk][1] = whh[kk * 2 + 1];
        B[kk] = bih[kk] + bhh[kk];
    }
    float4 r4[16];
    const float4* row4 = (const float4*)(xx + (size_t)n * ROW);
#pragma unroll
    for (int i = 0; i < 16; i++) r4[i] = row4[i];
    const float* row = (const float*)r4;

    float h0 = 0.f, h1 = 0.f, c0 = 0.f, c1 = 0.f;
#pragma unroll 4
    for (int t = 0; t < TT; t++) {
        float x0 = row[t * 2], x1 = row[t * 2 + 1];
        float g[8];
#pragma unroll
        for (int kk = 0; kk < 8; kk++)
            g[kk] = B[kk] + Wi[kk][0] * x0 + Wi[kk][1] * x1 + Wh[kk][0] * h0 + Wh[kk][1] * h1;
        float i0 = fsig(g[0]), i1 = fsig(g[1]);
        float f0 = fsig(g[2]), f1 = fsig(g[3]);
        float gg0 = ftanh(g[4]), gg1 = ftanh(g[5]);
        float o0 = fsig(g[6]), o1 = fsig(g[7]);
        c0 = f0 * c0 + i0 * gg0;
        c1 = f1 * c1 + i1 * gg1;
        h0 = o0 * ftanh(c0);
        h1 = o1 * ftanh(c1);
        *(float2*)(out + (size_t)t * (NN * FF) + n * 2) = make_float2(h0, h1);
    }
}

// ---------------------------------------------------------------------------
extern "C" void kernel_launch(void* const* d_in, const int* in_sizes, int n_in,
                              void* d_out, int out_size, void* d_ws, size_t ws_size,
                              hipStream_t stream) {
    const float* x    = (const float*)d_in[0];   // [T,N,F]
    const int*   ei   = (const int*)d_in[1];     // [2,E]
    const int*   mask = (const int*)d_in[2];     // [N]
    const float* wih  = (const float*)d_in[6];
    const float* whh  = (const float*)d_in[7];
    const float* bih  = (const float*)d_in[8];
    const float* bhh  = (const float*)d_in[9];
    float* out = (float*)d_out;                  // [T,N,F] fp32

    // ws: xx (25.6 MB) + fill_iter + wl_count + bsum + hz
    char* ws = (char*)d_ws;
    float* xx        = (float*)ws;
    int*   fill_iter = (int*)(ws + (size_t)NN * ROW * 4);
    int*   wl_count  = fill_iter + NN;
    int*   bsum      = wl_count + 32;
    unsigned char* hz = (unsigned char*)(bsum + 128);

    // d_out doubles as CSR/worklist scratch until k_lstm overwrites it (8 MB < 25.6 MB)
    int* csr    = (int*)d_out;                   // E ints (16B-aligned)
    int* wp     = csr + EE;                      // N     (16B-aligned)
    int* rowptr = wp + NN;                       // N+1   (16B-aligned)
    int* wl_a   = rowptr + NN + 4;               // N
    int* wl_b   = wl_a + NN;                     // N

    k_init<<<256, 256, 0, stream>>>(wp, wl_count);
    k_mt_flags<<<(NN + 63) / 64, 256, 0, stream>>>(x, mask, xx, fill_iter, hz);
    k_hist<<<1024, 256, 0, stream>>>(ei, hz, wp);
    k_scan1<<<NBLK, 256, 0, stream>>>(wp, bsum);
    k_scan3<<<NBLK, 256, 0, stream>>>(bsum, rowptr, wp);
    k_total<<<1, 128, 0, stream>>>(bsum, rowptr);
    k_csr_fill<<<1024, 256, 0, stream>>>(ei, hz, wp, csr);
    k_gather_first<<<6250, 256, 0, stream>>>(rowptr, csr, fill_iter, xx, wl_a, wl_count);
    k_gather_rest<<<1, 1024, 0, stream>>>(wl_a, wl_b, wl_count, rowptr, csr, fill_iter, xx);
    k_lstm<<<(NN + 255) / 256, 256, 0, stream>>>(xx, wih, whh, bih, bhh, out);
}

// Round 6
// 306.845 us; speedup vs baseline: 4.7288x; 1.0519x over previous
//
#include <hip/hip_runtime.h>
#include <math.h>

#define TT    32
#define NN    100000
#define FF    2
#define ROW   64        // TT*FF floats per node row
#define EE    1600000
#define MAXIT 20
#define LDSROW 66       // 64 + 2 pad: <=2-way LDS aliasing (free on CDNA4)
#define BIGIT (1 << 29) // fill_iter value for "no data yet"
#define NBLK  ((NN + 1023) / 1024)   // 98 scan blocks

typedef float f32x4 __attribute__((ext_vector_type(4)));
typedef float f32x2 __attribute__((ext_vector_type(2)));

__device__ __forceinline__ float fsig(float x) { return 1.0f / (1.0f + __expf(-x)); }
__device__ __forceinline__ float ftanh(float x) { return 2.0f / (1.0f + __expf(-2.0f * x)) - 1.0f; }

// ---------------------------------------------------------------------------
// Fused: mask + transpose [T,N,F]->[N][64] + fill_iter/hz flags + wp/wl zero.
__global__ void k_mt_flags(const float* __restrict__ x, const int* __restrict__ mask,
                           float* __restrict__ xx, int* __restrict__ fill_iter,
                           unsigned char* __restrict__ hz, int* __restrict__ wp,
                           int* __restrict__ wl_count) {
    __shared__ float tile[64 * LDSROW];
    const int n0 = blockIdx.x * 64;
    const int tid = threadIdx.x;

    // fused init (replaces k_init)
    if (tid < 64 && n0 + tid < NN) wp[n0 + tid] = 0;
    if (blockIdx.x == 0 && tid < 32) wl_count[tid] = 0;

#pragma unroll
    for (int r = 0; r < 16; r++) {
        int flat = r * 256 + tid;          // 0..4095
        int t = flat >> 7;
        int col = flat & 127;
        int gcol = n0 * 2 + col;
        if (gcol < NN * FF) {
            int n = n0 + (col >> 1);
            float v = __builtin_nontemporal_load(x + (size_t)t * (NN * FF) + gcol);
            v = mask[n] ? v : 0.0f;
            tile[(col >> 1) * LDSROW + t * 2 + (col & 1)] = v;
        }
    }
    __syncthreads();

    const int lane = tid & 63, w = tid >> 6;
    for (int i = 0; i < 16; i++) {
        int ln = w * 16 + i;
        int n = n0 + ln;
        if (n >= NN) break;                          // wave-uniform
        float v = tile[ln * LDSROW + lane];
        unsigned long long nzm = __ballot(v != 0.0f);
        if (lane == 0) {
            fill_iter[n] = (nzm != 0ull) ? 0 : BIGIT;
            hz[n] = (nzm != ~0ull) ? 1 : 0;          // row has at least one zero
        }
    }

#pragma unroll
    for (int j = 0; j < 4; j++) {
        int flat4 = j * 256 + tid;
        int ln = flat4 >> 4;
        int n = n0 + ln;
        if (n >= NN) continue;
        int off = (flat4 & 15) * 4;
        float4 v;
        v.x = tile[ln * LDSROW + off + 0];
        v.y = tile[ln * LDSROW + off + 1];
        v.z = tile[ln * LDSROW + off + 2];
        v.w = tile[ln * LDSROW + off + 3];
        *(float4*)(xx + (size_t)n * ROW + off) = v;
    }
}

// ---------------------------------------------------------------------------
// In-degree histogram over dst, ONLY for zero-having dst (others never fill).
__global__ void k_hist(const int* __restrict__ ei, const unsigned char* __restrict__ hz,
                       int* __restrict__ wp) {
    for (int e = blockIdx.x * blockDim.x + threadIdx.x; e < EE;
         e += gridDim.x * blockDim.x) {
        int dst = __builtin_nontemporal_load(ei + EE + e);
        if (hz[dst]) atomicAdd(&wp[dst], 1);
    }
}

// ---------------------------------------------------------------------------
// Two-level scan, stage 1: per-block sums (98 blocks x 256 thr, int4 loads).
__global__ void k_scan1(const int* __restrict__ wp, int* __restrict__ bsum) {
    __shared__ int wsum[4];
    int b = blockIdx.x, t = threadIdx.x;
    int idx = b * 1024 + t * 4;
    int s = 0;
    if (idx + 3 < NN) {
        int4 v = *(const int4*)(wp + idx);
        s = v.x + v.y + v.z + v.w;
    } else {
        for (int i = 0; i < 4; i++) if (idx + i < NN) s += wp[idx + i];
    }
#pragma unroll
    for (int d = 32; d > 0; d >>= 1) s += __shfl_down(s, d, 64);
    int lane = t & 63, w = t >> 6;
    if (lane == 0) wsum[w] = s;
    __syncthreads();
    if (t == 0) bsum[b] = wsum[0] + wsum[1] + wsum[2] + wsum[3];
}

// ---------------------------------------------------------------------------
// Stage 2 (fused): block offset from bsum tree-reduce + block-local exclusive
// scan + write rowptr and wp(=write cursor).
__global__ void k_scan3(const int* __restrict__ bsum,
                        int* __restrict__ rowptr, int* __restrict__ wp) {
    __shared__ int sh[128];
    __shared__ int wsum[4];
    int b = blockIdx.x, t = threadIdx.x;
    if (t < 128) sh[t] = (t < b) ? bsum[t] : 0;   // b < NBLK <= 128
    __syncthreads();
#pragma unroll
    for (int d = 64; d > 0; d >>= 1) {
        if (t < d) sh[t] += sh[t + d];
        __syncthreads();
    }
    int blockoff = sh[0];

    int lane = t & 63, w = t >> 6;
    int idx = b * 1024 + t * 4;
    int v0 = 0, v1 = 0, v2 = 0, v3 = 0;
    if (idx + 3 < NN) {
        int4 v = *(const int4*)(wp + idx);
        v0 = v.x; v1 = v.y; v2 = v.z; v3 = v.w;
    } else {
        if (idx + 0 < NN) v0 = wp[idx + 0];
        if (idx + 1 < NN) v1 = wp[idx + 1];
        if (idx + 2 < NN) v2 = wp[idx + 2];
        if (idx + 3 < NN) v3 = wp[idx + 3];
    }
    int tsum = v0 + v1 + v2 + v3;
    int incl = tsum;
#pragma unroll
    for (int d = 1; d < 64; d <<= 1) {
        int up = __shfl_up(incl, d, 64);
        if (lane >= d) incl += up;
    }
    if (lane == 63) wsum[w] = incl;
    __syncthreads();
    int woff = 0;
    for (int i = 0; i < w; i++) woff += wsum[i];
    int base = blockoff + woff + incl - tsum;     // exclusive prefix for v0
    if (idx + 0 < NN) { rowptr[idx + 0] = base;                wp[idx + 0] = base; }
    if (idx + 1 < NN) { rowptr[idx + 1] = base + v0;           wp[idx + 1] = base + v0; }
    if (idx + 2 < NN) { rowptr[idx + 2] = base + v0 + v1;      wp[idx + 2] = base + v0 + v1; }
    if (idx + 3 < NN) { rowptr[idx + 3] = base + v0 + v1 + v2; wp[idx + 3] = base + v0 + v1 + v2; }
}

// Tiny fixup: rowptr[NN] = total filtered edges (sum of all bsum).
__global__ void k_total(const int* __restrict__ bsum, int* __restrict__ rowptr) {
    __shared__ int sh[128];
    int t = threadIdx.x;
    if (t < 128) sh[t] = (t < NBLK) ? bsum[t] : 0;
    __syncthreads();
#pragma unroll
    for (int d = 64; d > 0; d >>= 1) {
        if (t < d) sh[t] += sh[t + d];
        __syncthreads();
    }
    if (t == 0) rowptr[NN] = sh[0];
}

// ---------------------------------------------------------------------------
// Bucket edges by dst (zero-having dst only): csr[rowptr[dst]..] = src list.
// NT loads keep the streaming ei out of L2 so dirty csr lines merge before
// writeback (round-5: 105->53 MB WRITE; this targets the remaining amp).
__global__ void k_csr_fill(const int* __restrict__ ei, const unsigned char* __restrict__ hz,
                           int* __restrict__ wp, int* __restrict__ csr) {
    for (int e = blockIdx.x * blockDim.x + threadIdx.x; e < EE;
         e += gridDim.x * blockDim.x) {
        int dst = __builtin_nontemporal_load(ei + EE + e);
        if (!hz[dst]) continue;
        int src = __builtin_nontemporal_load(ei + e);
        int pos = atomicAdd(&wp[dst], 1);
        csr[pos] = src;
    }
}

// ---------------------------------------------------------------------------
// Gather body, 4-way neighbor-parallel: lane = (g = lane>>4)*16 + (s = lane&15).
// Group g fetches neighbor (e+g)'s row as 16 x float4 -> 4 rows (16 cache
// lines) in flight per loop iter; cross-group reduce via 2 shfl_xor steps.
__device__ __forceinline__ void gather_node4(int n, int k, int lane,
                                             const int* __restrict__ rowptr,
                                             const int* __restrict__ csr,
                                             int* __restrict__ fill_iter,
                                             float* __restrict__ xx,
                                             int* __restrict__ wl_next,
                                             int* __restrict__ wl_count) {
    const int g = lane >> 4;
    const int s = lane & 15;
    int beg = rowptr[n], end = rowptr[n + 1];
    float ax = 0.f, ay = 0.f, az = 0.f, aw = 0.f, cntv = 0.f;
#pragma unroll 2
    for (int e = beg + g; e < end; e += 4) {
        int src = csr[e];                      // broadcast within group
        if (fill_iter[src] < k) {
            f32x4 v = ((const f32x4*)(xx + (size_t)src * ROW))[s];
            ax += v.x; ay += v.y; az += v.z; aw += v.w; cntv += 1.f;
        }
    }
    // reduce the 4 groups (lane xor 16, 32)
#pragma unroll
    for (int d = 16; d <= 32; d <<= 1) {
        ax += __shfl_xor(ax, d, 64);
        ay += __shfl_xor(ay, d, 64);
        az += __shfl_xor(az, d, 64);
        aw += __shfl_xor(aw, d, 64);
        cntv += __shfl_xor(cntv, d, 64);
    }
    f32x4 own = ((const f32x4*)(xx + (size_t)n * ROW))[s];
    bool has = cntv > 0.f;
    f32x4 nv;
    nv.x = (own.x == 0.f && has) ? ax / cntv : own.x;
    nv.y = (own.y == 0.f && has) ? ay / cntv : own.y;
    nv.z = (own.z == 0.f && has) ? az / cntv : own.z;
    nv.w = (own.w == 0.f && has) ? aw / cntv : own.w;
    bool allnz = (nv.x != 0.f) & (nv.y != 0.f) & (nv.z != 0.f) & (nv.w != 0.f);
    bool anynz = (nv.x != 0.f) | (nv.y != 0.f) | (nv.z != 0.f) | (nv.w != 0.f);
    unsigned long long ba = __ballot(allnz);
    unsigned long long bn = __ballot(anynz);
    if (g == 0) ((f32x4*)(xx + (size_t)n * ROW))[s] = nv;
    if (lane == 0) {
        if (bn != 0ull && fill_iter[n] > k) fill_iter[n] = k;   // now a valid source
        if (ba != ~0ull) {                     // still has zeros -> next worklist
            int pos = atomicAdd(&wl_count[k], 1);
            wl_next[pos] = n;
        }
    }
}

// ---------------------------------------------------------------------------
// Iteration 1: hz-flagged nodes only (1-byte check, no row read for others).
__global__ void k_gather_first(const unsigned char* __restrict__ hz,
                               const int* __restrict__ rowptr, const int* __restrict__ csr,
                               int* __restrict__ fill_iter, float* __restrict__ xx,
                               int* __restrict__ wl_next, int* __restrict__ wl_count) {
    const int lane = threadIdx.x & 63;
    int wave = (blockIdx.x * blockDim.x + threadIdx.x) >> 6;
    const int nwaves = (gridDim.x * blockDim.x) >> 6;
    for (int n0 = wave; n0 < NN; n0 += nwaves) {
        int n = __builtin_amdgcn_readfirstlane(n0);
        if (!hz[n]) continue;                  // wave-uniform scalar check
        gather_node4(n, 1, lane, rowptr, csr, fill_iter, xx, wl_next, wl_count);
    }
}

// ---------------------------------------------------------------------------
// Iterations 2..MAXIT in ONE persistent single-block kernel (worklist is tiny
// after iter 1: only nodes with zero valid neighbors remain).
__global__ __launch_bounds__(1024)
void k_gather_rest(int* __restrict__ wl_a, int* __restrict__ wl_b,
                   int* __restrict__ wl_count,
                   const int* __restrict__ rowptr, const int* __restrict__ csr,
                   int* __restrict__ fill_iter, float* __restrict__ xx) {
    const int lane = threadIdx.x & 63;
    const int wave = threadIdx.x >> 6;       // 0..15
    for (int k = 2; k <= MAXIT; k++) {
        int cnt = atomicAdd(&wl_count[k - 1], 0);   // L2 read, never stale-L1
        if (cnt == 0) break;                        // uniform across block
        int* prev = (k & 1) ? wl_b : wl_a;          // k=2 reads wl_a
        int* next = (k & 1) ? wl_a : wl_b;
        for (int w = wave; w < cnt; w += 16) {
            int n = __builtin_amdgcn_readfirstlane(prev[w]);
            gather_node4(n, k, lane, rowptr, csr, fill_iter, xx, next, wl_count);
        }
        __threadfence();
        __syncthreads();
    }
}

// ---------------------------------------------------------------------------
// LSTM: one thread per node, hidden=2, gates i,f,g,o. NT loads/stores (both
// streams are touch-once).
__global__ void k_lstm(const float* __restrict__ xx,
                       const float* __restrict__ wih, const float* __restrict__ whh,
                       const float* __restrict__ bih, const float* __restrict__ bhh,
                       float* __restrict__ out) {
    int n = blockIdx.x * blockDim.x + threadIdx.x;
    if (n >= NN) return;
    float Wi[8][2], Wh[8][2], B[8];
#pragma unroll
    for (int kk = 0; kk < 8; kk++) {
        Wi[kk][0] = wih[kk * 2]; Wi[kk][1] = wih[kk * 2 + 1];
        Wh[kk][0] = whh[kk * 2]; Wh[kk][1] = whh[kk * 2 + 1];
        B[kk] = bih[kk] + bhh[kk];
    }
    f32x4 r4[16];
    const f32x4* row4 = (const f32x4*)(xx + (size_t)n * ROW);
#pragma unroll
    for (int i = 0; i < 16; i++) r4[i] = __builtin_nontemporal_load(row4 + i);
    const float* row = (const float*)r4;

    float h0 = 0.f, h1 = 0.f, c0 = 0.f, c1 = 0.f;
#pragma unroll 4
    for (int t = 0; t < TT; t++) {
        float x0 = row[t * 2], x1 = row[t * 2 + 1];
        float g[8];
#pragma unroll
        for (int kk = 0; kk < 8; kk++)
            g[kk] = B[kk] + Wi[kk][0] * x0 + Wi[kk][1] * x1 + Wh[kk][0] * h0 + Wh[kk][1] * h1;
        float i0 = fsig(g[0]), i1 = fsig(g[1]);
        float f0 = fsig(g[2]), f1 = fsig(g[3]);
        float gg0 = ftanh(g[4]), gg1 = ftanh(g[5]);
        float o0 = fsig(g[6]), o1 = fsig(g[7]);
        c0 = f0 * c0 + i0 * gg0;
        c1 = f1 * c1 + i1 * gg1;
        h0 = o0 * ftanh(c0);
        h1 = o1 * ftanh(c1);
        f32x2 hv; hv.x = h0; hv.y = h1;
        __builtin_nontemporal_store(hv, (f32x2*)(out + (size_t)t * (NN * FF) + n * 2));
    }
}

// ---------------------------------------------------------------------------
extern "C" void kernel_launch(void* const* d_in, const int* in_sizes, int n_in,
                              void* d_out, int out_size, void* d_ws, size_t ws_size,
                              hipStream_t stream) {
    const float* x    = (const float*)d_in[0];   // [T,N,F]
    const int*   ei   = (const int*)d_in[1];     // [2,E]
    const int*   mask = (const int*)d_in[2];     // [N]
    const float* wih  = (const float*)d_in[6];
    const float* whh  = (const float*)d_in[7];
    const float* bih  = (const float*)d_in[8];
    const float* bhh  = (const float*)d_in[9];
    float* out = (float*)d_out;                  // [T,N,F] fp32

    // ws: xx (25.6 MB) + fill_iter + wl_count + bsum + hz
    char* ws = (char*)d_ws;
    float* xx        = (float*)ws;
    int*   fill_iter = (int*)(ws + (size_t)NN * ROW * 4);
    int*   wl_count  = fill_iter + NN;
    int*   bsum      = wl_count + 32;
    unsigned char* hz = (unsigned char*)(bsum + 128);

    // d_out doubles as CSR/worklist scratch until k_lstm overwrites it (8 MB < 25.6 MB)
    int* csr    = (int*)d_out;                   // E ints (16B-aligned)
    int* wp     = csr + EE;                      // N     (16B-aligned)
    int* rowptr = wp + NN;                       // N+1   (16B-aligned)
    int* wl_a   = rowptr + NN + 4;               // N
    int* wl_b   = wl_a + NN;                     // N

    k_mt_flags<<<(NN + 63) / 64, 256, 0, stream>>>(x, mask, xx, fill_iter, hz, wp, wl_count);
    k_hist<<<1024, 256, 0, stream>>>(ei, hz, wp);
    k_scan1<<<NBLK, 256, 0, stream>>>(wp, bsum);
    k_scan3<<<NBLK, 256, 0, stream>>>(bsum, rowptr, wp);
    k_total<<<1, 128, 0, stream>>>(bsum, rowptr);
    k_csr_fill<<<1024, 256, 0, stream>>>(ei, hz, wp, csr);
    k_gather_first<<<6250, 256, 0, stream>>>(hz, rowptr, csr, fill_iter, xx, wl_a, wl_count);
    k_gather_rest<<<1, 1024, 0, stream>>>(wl_a, wl_b, wl_count, rowptr, csr, fill_iter, xx);
    k_lstm<<<(NN + 255) / 256, 256, 0, stream>>>(xx, wih, whh, bih, bhh, out);
}

// Round 7
// 284.267 us; speedup vs baseline: 5.1044x; 1.0794x over previous
//
#include <hip/hip_runtime.h>
#include <math.h>

#define TT    32
#define NN    100000
#define FF    2
#define ROW   64        // TT*FF floats per node row
#define EE    1600000
#define MAXIT 20
#define LDSROW 66       // 64 + 2 pad: <=2-way LDS aliasing (free on CDNA4)
#define BIGIT (1 << 29) // fill_iter value for "no data yet"
#define MM    (2 * NN)  // concatenated valid/invalid counter array
#define NBLK2 ((MM + 1023) / 1024)   // 196 scan blocks

typedef float f32x4 __attribute__((ext_vector_type(4)));
typedef float f32x2 __attribute__((ext_vector_type(2)));

__device__ __forceinline__ float fsig(float x) { return 1.0f / (1.0f + __expf(-x)); }
__device__ __forceinline__ float ftanh(float x) { return 2.0f / (1.0f + __expf(-2.0f * x)) - 1.0f; }

// ---------------------------------------------------------------------------
// Fused: mask + transpose [T,N,F]->[N][64] + fill_iter/hz/hd flags + wp2/wl zero.
__global__ void k_mt_flags(const float* __restrict__ x, const int* __restrict__ mask,
                           float* __restrict__ xx, int* __restrict__ fill_iter,
                           unsigned char* __restrict__ hz, unsigned char* __restrict__ hd,
                           int* __restrict__ wp2, int* __restrict__ wl_count) {
    __shared__ float tile[64 * LDSROW];
    const int n0 = blockIdx.x * 64;
    const int tid = threadIdx.x;

    // fused init: zero both halves of wp2 + wl_count
    if (tid < 64 && n0 + tid < NN) { wp2[n0 + tid] = 0; wp2[NN + n0 + tid] = 0; }
    if (blockIdx.x == 0 && tid < 32) wl_count[tid] = 0;

#pragma unroll
    for (int r = 0; r < 16; r++) {
        int flat = r * 256 + tid;          // 0..4095
        int t = flat >> 7;
        int col = flat & 127;
        int gcol = n0 * 2 + col;
        if (gcol < NN * FF) {
            int n = n0 + (col >> 1);
            float v = __builtin_nontemporal_load(x + (size_t)t * (NN * FF) + gcol);
            v = mask[n] ? v : 0.0f;
            tile[(col >> 1) * LDSROW + t * 2 + (col & 1)] = v;
        }
    }
    __syncthreads();

    const int lane = tid & 63, w = tid >> 6;
    for (int i = 0; i < 16; i++) {
        int ln = w * 16 + i;
        int n = n0 + ln;
        if (n >= NN) break;                          // wave-uniform
        float v = tile[ln * LDSROW + lane];
        unsigned long long nzm = __ballot(v != 0.0f);
        if (lane == 0) {
            fill_iter[n] = (nzm != 0ull) ? 0 : BIGIT;
            hz[n] = (nzm != ~0ull) ? 1 : 0;          // row has at least one zero
            hd[n] = (nzm != 0ull) ? 1 : 0;           // row has at least one datum
        }
    }

#pragma unroll
    for (int j = 0; j < 4; j++) {
        int flat4 = j * 256 + tid;
        int ln = flat4 >> 4;
        int n = n0 + ln;
        if (n >= NN) continue;
        int off = (flat4 & 15) * 4;
        float4 v;
        v.x = tile[ln * LDSROW + off + 0];
        v.y = tile[ln * LDSROW + off + 1];
        v.z = tile[ln * LDSROW + off + 2];
        v.w = tile[ln * LDSROW + off + 3];
        *(float4*)(xx + (size_t)n * ROW + off) = v;
    }
}

// ---------------------------------------------------------------------------
// Histogram split by src validity: wp2[dst] (valid src) / wp2[NN+dst] (invalid).
__global__ void k_hist(const int* __restrict__ ei, const unsigned char* __restrict__ hz,
                       const unsigned char* __restrict__ hd, int* __restrict__ wp2) {
    for (int e = blockIdx.x * blockDim.x + threadIdx.x; e < EE;
         e += gridDim.x * blockDim.x) {
        int dst = __builtin_nontemporal_load(ei + EE + e);
        if (!hz[dst]) continue;
        int src = __builtin_nontemporal_load(ei + e);
        atomicAdd(hd[src] ? &wp2[dst] : &wp2[NN + dst], 1);
    }
}

// ---------------------------------------------------------------------------
// Two-level scan over MM=2N counters, stage 1: per-block sums.
__global__ void k_scan1(const int* __restrict__ wp2, int* __restrict__ bsum) {
    __shared__ int wsum[4];
    int b = blockIdx.x, t = threadIdx.x;
    int idx = b * 1024 + t * 4;
    int s = 0;
    if (idx + 3 < MM) {
        int4 v = *(const int4*)(wp2 + idx);
        s = v.x + v.y + v.z + v.w;
    } else {
        for (int i = 0; i < 4; i++) if (idx + i < MM) s += wp2[idx + i];
    }
#pragma unroll
    for (int d = 32; d > 0; d >>= 1) s += __shfl_down(s, d, 64);
    int lane = t & 63, w = t >> 6;
    if (lane == 0) wsum[w] = s;
    __syncthreads();
    if (t == 0) bsum[b] = wsum[0] + wsum[1] + wsum[2] + wsum[3];
}

// ---------------------------------------------------------------------------
// Stage 2: block offset (tree over 256 slots) + block-local exclusive scan.
// Writes sc (rowptr) and wp2 (write cursors).
__global__ void k_scan3(const int* __restrict__ bsum,
                        int* __restrict__ sc, int* __restrict__ wp2) {
    __shared__ int sh[256];
    __shared__ int wsum[4];
    int b = blockIdx.x, t = threadIdx.x;
    sh[t] = (t < b) ? bsum[t] : 0;               // b < NBLK2 <= 256
    __syncthreads();
#pragma unroll
    for (int d = 128; d > 0; d >>= 1) {
        if (t < d) sh[t] += sh[t + d];
        __syncthreads();
    }
    int blockoff = sh[0];

    int lane = t & 63, w = t >> 6;
    int idx = b * 1024 + t * 4;
    int v0 = 0, v1 = 0, v2 = 0, v3 = 0;
    if (idx + 3 < MM) {
        int4 v = *(const int4*)(wp2 + idx);
        v0 = v.x; v1 = v.y; v2 = v.z; v3 = v.w;
    } else {
        if (idx + 0 < MM) v0 = wp2[idx + 0];
        if (idx + 1 < MM) v1 = wp2[idx + 1];
        if (idx + 2 < MM) v2 = wp2[idx + 2];
        if (idx + 3 < MM) v3 = wp2[idx + 3];
    }
    int tsum = v0 + v1 + v2 + v3;
    int incl = tsum;
#pragma unroll
    for (int d = 1; d < 64; d <<= 1) {
        int up = __shfl_up(incl, d, 64);
        if (lane >= d) incl += up;
    }
    if (lane == 63) wsum[w] = incl;
    __syncthreads();
    int woff = 0;
    for (int i = 0; i < w; i++) woff += wsum[i];
    int base = blockoff + woff + incl - tsum;     // exclusive prefix for v0
    if (idx + 0 < MM) { sc[idx + 0] = base;                wp2[idx + 0] = base; }
    if (idx + 1 < MM) { sc[idx + 1] = base + v0;           wp2[idx + 1] = base + v0; }
    if (idx + 2 < MM) { sc[idx + 2] = base + v0 + v1;      wp2[idx + 2] = base + v0 + v1; }
    if (idx + 3 < MM) { sc[idx + 3] = base + v0 + v1 + v2; wp2[idx + 3] = base + v0 + v1 + v2; }
}

// Tiny fixup: sc[MM] = total filtered edges.
__global__ void k_total(const int* __restrict__ bsum, int* __restrict__ sc) {
    __shared__ int sh[256];
    int t = threadIdx.x;
    sh[t] = (t < NBLK2) ? bsum[t] : 0;
    __syncthreads();
#pragma unroll
    for (int d = 128; d > 0; d >>= 1) {
        if (t < d) sh[t] += sh[t + d];
        __syncthreads();
    }
    if (t == 0) sc[MM] = sh[0];
}

// ---------------------------------------------------------------------------
// Bucket edges: valid-src -> csr[sc[dst]..], invalid-src -> csr[sc[NN+dst]..].
__global__ void k_csr_fill(const int* __restrict__ ei, const unsigned char* __restrict__ hz,
                           const unsigned char* __restrict__ hd,
                           int* __restrict__ wp2, int* __restrict__ csr) {
    for (int e = blockIdx.x * blockDim.x + threadIdx.x; e < EE;
         e += gridDim.x * blockDim.x) {
        int dst = __builtin_nontemporal_load(ei + EE + e);
        if (!hz[dst]) continue;
        int src = __builtin_nontemporal_load(ei + e);
        int pos = atomicAdd(hd[src] ? &wp2[dst] : &wp2[NN + dst], 1);
        csr[pos] = src;
    }
}

// ---------------------------------------------------------------------------
// Gather body, 4-way neighbor-parallel. Valid extent needs NO per-edge check
// (all sources have data by construction); invalid extent checks fill_iter<k
// (empty at iter 1 -> pass ibeg==iend).
__device__ __forceinline__ void gather_node4(int n, int k, int lane,
                                             int vbeg, int vend, int ibeg, int iend,
                                             const int* __restrict__ csr,
                                             int* __restrict__ fill_iter,
                                             float* __restrict__ xx,
                                             int* __restrict__ wl_next,
                                             int* __restrict__ wl_count) {
    const int g = lane >> 4;
    const int s = lane & 15;
    float ax = 0.f, ay = 0.f, az = 0.f, aw = 0.f, cntv = 0.f;
#pragma unroll 2
    for (int e = vbeg + g; e < vend; e += 4) {
        int src = csr[e];                      // broadcast within group
        f32x4 v = ((const f32x4*)(xx + (size_t)src * ROW))[s];
        ax += v.x; ay += v.y; az += v.z; aw += v.w; cntv += 1.f;
    }
    for (int e = ibeg + g; e < iend; e += 4) {
        int src = csr[e];
        if (fill_iter[src] < k) {
            f32x4 v = ((const f32x4*)(xx + (size_t)src * ROW))[s];
            ax += v.x; ay += v.y; az += v.z; aw += v.w; cntv += 1.f;
        }
    }
    // reduce the 4 groups (lane xor 16, 32)
#pragma unroll
    for (int d = 16; d <= 32; d <<= 1) {
        ax += __shfl_xor(ax, d, 64);
        ay += __shfl_xor(ay, d, 64);
        az += __shfl_xor(az, d, 64);
        aw += __shfl_xor(aw, d, 64);
        cntv += __shfl_xor(cntv, d, 64);
    }
    f32x4 own = ((const f32x4*)(xx + (size_t)n * ROW))[s];
    bool has = cntv > 0.f;
    f32x4 nv;
    nv.x = (own.x == 0.f && has) ? ax / cntv : own.x;
    nv.y = (own.y == 0.f && has) ? ay / cntv : own.y;
    nv.z = (own.z == 0.f && has) ? az / cntv : own.z;
    nv.w = (own.w == 0.f && has) ? aw / cntv : own.w;
    bool allnz = (nv.x != 0.f) & (nv.y != 0.f) & (nv.z != 0.f) & (nv.w != 0.f);
    bool anynz = (nv.x != 0.f) | (nv.y != 0.f) | (nv.z != 0.f) | (nv.w != 0.f);
    unsigned long long ba = __ballot(allnz);
    unsigned long long bn = __ballot(anynz);
    if (g == 0) ((f32x4*)(xx + (size_t)n * ROW))[s] = nv;
    if (lane == 0) {
        if (bn != 0ull && fill_iter[n] > k) fill_iter[n] = k;   // now a valid source
        if (ba != ~0ull) {                     // still has zeros -> next worklist
            int pos = atomicAdd(&wl_count[k], 1);
            wl_next[pos] = n;
        }
    }
}

// ---------------------------------------------------------------------------
// Iteration 1: hz-flagged nodes only; valid CSR only (check-free hot loop).
__global__ void k_gather_first(const unsigned char* __restrict__ hz,
                               const int* __restrict__ sc, const int* __restrict__ csr,
                               int* __restrict__ fill_iter, float* __restrict__ xx,
                               int* __restrict__ wl_next, int* __restrict__ wl_count) {
    const int lane = threadIdx.x & 63;
    int wave = (blockIdx.x * blockDim.x + threadIdx.x) >> 6;
    const int nwaves = (gridDim.x * blockDim.x) >> 6;
    for (int n0 = wave; n0 < NN; n0 += nwaves) {
        int n = __builtin_amdgcn_readfirstlane(n0);
        if (!hz[n]) continue;                  // wave-uniform scalar check
        gather_node4(n, 1, lane, sc[n], sc[n + 1], 0, 0,
                     csr, fill_iter, xx, wl_next, wl_count);
    }
}

// ---------------------------------------------------------------------------
// Iterations 2..MAXIT in ONE persistent single-block kernel (worklist after
// iter 1 is ~nodes with zero valid neighbors: expected ~1 node).
__global__ __launch_bounds__(1024)
void k_gather_rest(int* __restrict__ wl_a, int* __restrict__ wl_b,
                   int* __restrict__ wl_count,
                   const int* __restrict__ sc, const int* __restrict__ csr,
                   int* __restrict__ fill_iter, float* __restrict__ xx) {
    const int lane = threadIdx.x & 63;
    const int wave = threadIdx.x >> 6;       // 0..15
    for (int k = 2; k <= MAXIT; k++) {
        int cnt = atomicAdd(&wl_count[k - 1], 0);   // L2 read, never stale-L1
        if (cnt == 0) break;                        // uniform across block
        int* prev = (k & 1) ? wl_b : wl_a;          // k=2 reads wl_a
        int* next = (k & 1) ? wl_a : wl_b;
        for (int w = wave; w < cnt; w += 16) {
            int n = __builtin_amdgcn_readfirstlane(prev[w]);
            gather_node4(n, k, lane, sc[n], sc[n + 1], sc[NN + n], sc[NN + n + 1],
                         csr, fill_iter, xx, next, wl_count);
        }
        __threadfence();
        __syncthreads();
    }
}

// ---------------------------------------------------------------------------
// LSTM: one thread per node, hidden=2, gates i,f,g,o. NT loads/stores.
__global__ void k_lstm(const float* __restrict__ xx,
                       const float* __restrict__ wih, const float* __restrict__ whh,
                       const float* __restrict__ bih, const float* __restrict__ bhh,
                       float* __restrict__ out) {
    int n = blockIdx.x * blockDim.x + threadIdx.x;
    if (n >= NN) return;
    float Wi[8][2], Wh[8][2], B[8];
#pragma unroll
    for (int kk = 0; kk < 8; kk++) {
        Wi[kk][0] = wih[kk * 2]; Wi[kk][1] = wih[kk * 2 + 1];
        Wh[kk][0] = whh[kk * 2]; Wh[kk][1] = whh[kk * 2 + 1];
        B[kk] = bih[kk] + bhh[kk];
    }
    f32x4 r4[16];
    const f32x4* row4 = (const f32x4*)(xx + (size_t)n * ROW);
#pragma unroll
    for (int i = 0; i < 16; i++) r4[i] = __builtin_nontemporal_load(row4 + i);
    const float* row = (const float*)r4;

    float h0 = 0.f, h1 = 0.f, c0 = 0.f, c1 = 0.f;
#pragma unroll 4
    for (int t = 0; t < TT; t++) {
        float x0 = row[t * 2], x1 = row[t * 2 + 1];
        float g[8];
#pragma unroll
        for (int kk = 0; kk < 8; kk++)
            g[kk] = B[kk] + Wi[kk][0] * x0 + Wi[kk][1] * x1 + Wh[kk][0] * h0 + Wh[kk][1] * h1;
        float i0 = fsig(g[0]), i1 = fsig(g[1]);
        float f0 = fsig(g[2]), f1 = fsig(g[3]);
        float gg0 = ftanh(g[4]), gg1 = ftanh(g[5]);
        float o0 = fsig(g[6]), o1 = fsig(g[7]);
        c0 = f0 * c0 + i0 * gg0;
        c1 = f1 * c1 + i1 * gg1;
        h0 = o0 * ftanh(c0);
        h1 = o1 * ftanh(c1);
        f32x2 hv; hv.x = h0; hv.y = h1;
        __builtin_nontemporal_store(hv, (f32x2*)(out + (size_t)t * (NN * FF) + n * 2));
    }
}

// ---------------------------------------------------------------------------
extern "C" void kernel_launch(void* const* d_in, const int* in_sizes, int n_in,
                              void* d_out, int out_size, void* d_ws, size_t ws_size,
                              hipStream_t stream) {
    const float* x    = (const float*)d_in[0];   // [T,N,F]
    const int*   ei   = (const int*)d_in[1];     // [2,E]
    const int*   mask = (const int*)d_in[2];     // [N]
    const float* wih  = (const float*)d_in[6];
    const float* whh  = (const float*)d_in[7];
    const float* bih  = (const float*)d_in[8];
    const float* bhh  = (const float*)d_in[9];
    float* out = (float*)d_out;                  // [T,N,F] fp32

    // ws: xx (25.6 MB) + fill_iter + wl_count + bsum + hz + hd
    char* ws = (char*)d_ws;
    float* xx        = (float*)ws;
    int*   fill_iter = (int*)(ws + (size_t)NN * ROW * 4);
    int*   wl_count  = fill_iter + NN;
    int*   bsum      = wl_count + 32;
    unsigned char* hz = (unsigned char*)(bsum + 256);
    unsigned char* hd = hz + ((NN + 15) & ~15);

    // d_out doubles as CSR/worklist scratch until k_lstm overwrites it (<9 MB < 25.6 MB)
    int* csr  = (int*)d_out;                     // <= E ints (16B-aligned)
    int* wp2  = csr + EE;                        // 2N cursors (16B-aligned)
    int* sc   = wp2 + MM;                        // 2N+1 rowptr (16B-aligned)
    int* wl_a = sc + MM + 4;                     // N
    int* wl_b = wl_a + NN;                       // N

    k_mt_flags<<<(NN + 63) / 64, 256, 0, stream>>>(x, mask, xx, fill_iter, hz, hd, wp2, wl_count);
    k_hist<<<2048, 256, 0, stream>>>(ei, hz, hd, wp2);
    k_scan1<<<NBLK2, 256, 0, stream>>>(wp2, bsum);
    k_scan3<<<NBLK2, 256, 0, stream>>>(bsum, sc, wp2);
    k_total<<<1, 256, 0, stream>>>(bsum, sc);
    k_csr_fill<<<2048, 256, 0, stream>>>(ei, hz, hd, wp2, csr);
    k_gather_first<<<6250, 256, 0, stream>>>(hz, sc, csr, fill_iter, xx, wl_a, wl_count);
    k_gather_rest<<<1, 1024, 0, stream>>>(wl_a, wl_b, wl_count, sc, csr, fill_iter, xx);
    k_lstm<<<(NN + 255) / 256, 256, 0, stream>>>(xx, wih, whh, bih, bhh, out);
}